// Round 6
// baseline (447.460 us; speedup 1.0000x reference)
//
#include <hip/hip_runtime.h>

#define ND   2048
#define BB   16384

typedef unsigned short u16;
typedef unsigned int u32;
typedef __attribute__((ext_vector_type(8))) short short8;
typedef __attribute__((ext_vector_type(4))) float f32x4;

__device__ inline float bf2f(u16 u) {
    union { u32 i; float f; } v; v.i = ((u32)u) << 16; return v.f;
}
__device__ inline u16 f2bf(float f) {
    union { float f; u32 i; } v; v.f = f;
    u32 i = v.i + 0x7fffu + ((v.i >> 16) & 1u);
    return (u16)(i >> 16);
}
__device__ inline float seluf(float x) {
    const float sc = 1.0507009873554805f, al = 1.6732632423543772f;
    return x > 0.f ? sc * x : sc * al * expm1f(x);
}

// ---------------- dtype sniffer ----------------
__global__ void detectk(const void* __restrict__ demb, u32* __restrict__ flag) {
    const u16* p = (const u16*)demb;
    int tid = threadIdx.x;  // 256
    int sane = 0;
    #pragma unroll
    for (int i = 0; i < 2; i++) {
        u16 u = p[4 * tid + 2 * i];
        int e = (u >> 7) & 0xFF;
        if (u == 0 || (e >= 0x66 && e <= 0x8C)) sane++;
    }
    __shared__ int red[256];
    red[tid] = sane; __syncthreads();
    for (int o = 128; o > 0; o >>= 1) {
        if (tid < o) red[tid] += red[tid + o];
        __syncthreads();
    }
    if (tid == 0) flag[0] = (red[0] < 300) ? 1u : 0u;
}

// ---------------- canonical bf16 conversion (26 segments, one launch) -------
#define NSEG 26
struct CvtArgs { const void* src[NSEG]; int off[NSEG]; int n[NSEG]; };

__global__ __launch_bounds__(256) void cvtk(CvtArgs a, u16* __restrict__ base,
                                            const u32* __restrict__ flag) {
    int seg = blockIdx.y;
    int n = a.n[seg];
    const void* s = a.src[seg];
    u16* d = base + a.off[seg];
    bool f32 = flag[0] != 0;
    int stride = gridDim.x * blockDim.x;
    for (int i = blockIdx.x * blockDim.x + threadIdx.x; i < n; i += stride)
        d[i] = f32 ? f2bf(((const float*)s)[i]) : ((const u16*)s)[i];
}

// ---------------- transpose (bf16, tiled 32x32) ----------------
__device__ inline void tpose_body(const u16* in, int R, int C,
                                  u16* out, int ldo, int ooff,
                                  u16 (*tile)[33]) {
    int c0 = blockIdx.x * 32, r0 = blockIdx.y * 32;
    int x = c0 + threadIdx.x;
    for (int i = threadIdx.y; i < 32; i += 8) {
        int r = r0 + i;
        tile[i][threadIdx.x] = (r < R && x < C) ? in[(size_t)r * C + x] : (u16)0;
    }
    __syncthreads();
    int rr = r0 + threadIdx.x;
    for (int i = threadIdx.y; i < 32; i += 8) {
        int cc = c0 + i;
        if (cc < C && rr < R) out[(size_t)cc * ldo + ooff + rr] = tile[threadIdx.x][i];
    }
}

__global__ void tpose_embs(const u16* __restrict__ demb, const u16* __restrict__ pemb,
                           u16* __restrict__ disT, u16* __restrict__ drugT) {
    __shared__ u16 tile[32][33];
    if (blockIdx.z == 0) tpose_body(demb, ND, 128, disT, ND, 0, tile);
    else                 tpose_body(pemb, ND, 128, drugT, ND, 0, tile);
}

__global__ void tpose_smalls(const u16* s0, const u16* s1, const u16* s2,
                             const u16* s3, const u16* s4, const u16* s5,
                             u16* W1T, u16* W2T, u16* WcTe, u16* WcTp) {
    __shared__ u16 tile[32][33];
    const u16* in; u16* out; int ldo, ooff;
    switch (blockIdx.z) {
        case 0:  in = s0; out = W1T;  ldo = 128; ooff = 0;   break;
        case 1:  in = s1; out = W2T;  ldo = 128; ooff = 0;   break;
        case 2:  in = s2; out = WcTe; ldo = 256; ooff = 0;   break;
        case 3:  in = s3; out = WcTe; ldo = 256; ooff = 128; break;
        case 4:  in = s4; out = WcTp; ldo = 256; ooff = 0;   break;
        default: in = s5; out = WcTp; ldo = 256; ooff = 128; break;
    }
    tpose_body(in, 128, 128, out, ldo, ooff, tile);
}

// ---------------- combined biases ----------------
__global__ void biasc(const u16* a0, const u16* a1, const u16* a2, u16* o0,
                      const u16* b0, const u16* b1, const u16* b2, u16* o1) {
    int t = threadIdx.x;  // 128
    o0[t] = f2bf(bf2f(a0[t]) + bf2f(a1[t]) + bf2f(a2[t]));
    o1[t] = f2bf(bf2f(b0[t]) + bf2f(b1[t]) + bf2f(b2[t]));
}

// ---------------- inverse degree (flag-dispatched adjacency dtype) ----------
__global__ __launch_bounds__(256) void degk(
    const void* __restrict__ e_e, float* __restrict__ dinv_e,
    const void* __restrict__ p_p, float* __restrict__ dinv_p,
    const u32* __restrict__ flag) {
    int row = blockIdx.x, tid = threadIdx.x;
    const void* ab = blockIdx.y ? p_p : e_e;
    float* o = blockIdx.y ? dinv_p : dinv_e;
    bool f32 = flag[0] != 0;
    float s = 0.f;
    if (f32) {
        const float4* a4 = (const float4*)((const float*)ab + (size_t)row * 2048) + tid * 2;
        float4 v0 = a4[0], v1 = a4[1];
        s = v0.x + v0.y + v0.z + v0.w + v1.x + v1.y + v1.z + v1.w;
    } else {
        const uint4* a4 = (const uint4*)((const u16*)ab + (size_t)row * 2048) + tid;
        uint4 v = a4[0];
        u32 u[4] = {v.x, v.y, v.z, v.w};
        #pragma unroll
        for (int c = 0; c < 4; c++)
            s += bf2f((u16)(u[c] & 0xffff)) + bf2f((u16)(u[c] >> 16));
    }
    __shared__ float red[256];
    red[tid] = s; __syncthreads();
    for (int ofs = 128; ofs > 0; ofs >>= 1) {
        if (tid < ofs) red[tid] += red[tid + ofs];
        __syncthreads();
    }
    if (tid == 0) o[row] = 1.f / (red[0] + 1e-8f);
}

// ---------------- ko / qs projections: emb[2048,128] @ W[128,32] (+bias) ----
__global__ __launch_bounds__(128) void koqs(
    const u16* __restrict__ demb, const u16* __restrict__ pemb,
    const u16* __restrict__ Wa1d, const u16* __restrict__ ba1d,
    const u16* __restrict__ Wa1p, const u16* __restrict__ ba1p,
    float* __restrict__ ko_d, float* __restrict__ qs_d,
    float* __restrict__ ko_p, float* __restrict__ qs_p) {
    int row = blockIdx.x, m = blockIdx.y, tid = threadIdx.x;
    const u16* src; const u16* W; const u16* bias; float* out;
    switch (m) {
        case 0:  src = pemb; W = Wa1d;            bias = nullptr; out = ko_d; break;
        case 1:  src = demb; W = Wa1d + 128 * 32; bias = ba1d;    out = qs_d; break;
        case 2:  src = demb; W = Wa1p;            bias = nullptr; out = ko_p; break;
        default: src = pemb; W = Wa1p + 128 * 32; bias = ba1p;    out = qs_p; break;
    }
    __shared__ float x[128];
    __shared__ float red[128];
    x[tid] = bf2f(src[(size_t)row * 128 + tid]);
    __syncthreads();
    int a = tid & 31, part = tid >> 5;
    float s = 0.f;
    #pragma unroll
    for (int k = 0; k < 32; k++) s += x[part * 32 + k] * bf2f(W[(part * 32 + k) * 32 + a]);
    red[tid] = s;
    __syncthreads();
    if (part == 0) {
        float t = red[a] + red[a + 32] + red[a + 64] + red[a + 96];
        if (bias) t += bf2f(bias[a]);
        out[(size_t)row * 32 + a] = t;
    }
}

// ---------------- attention: unnormalized exp weights + row inverse sums ----
// e(row,j) = exp( relu(score)*adj )  ( = 1 for non-edges since score>=0 )
// rinv[row] = 1 / sum_j e(row,j).   Normalization applied in GEMM rowscale.
__global__ __launch_bounds__(256) void attnw2(
    const float* __restrict__ qs, const float* __restrict__ ko,
    const void* __restrict__ adjv, int rs, int cs,
    const u16* __restrict__ w2, const u16* __restrict__ b2p,
    u16* __restrict__ outw, float* __restrict__ rinv,
    const u32* __restrict__ flag) {
    __shared__ float qv[128];
    __shared__ float w2v[32];
    __shared__ float red[256];
    int tid = threadIdx.x;
    int row0 = blockIdx.x * 4;
    bool f32a = flag[0] != 0;
    if (tid < 128) qv[tid] = qs[(size_t)row0 * 32 + tid];
    if (tid < 32) w2v[tid] = bf2f(w2[tid]);
    __syncthreads();
    float b2 = bf2f(b2p[0]);
    float ls[4] = {0.f, 0.f, 0.f, 0.f};
    for (int j = tid; j < 2048; j += 256) {
        const float4* kp = (const float4*)(ko + (size_t)j * 32);
        float kk[32];
        #pragma unroll
        for (int q = 0; q < 8; q++) {
            float4 v = kp[q];
            kk[q * 4] = v.x; kk[q * 4 + 1] = v.y; kk[q * 4 + 2] = v.z; kk[q * 4 + 3] = v.w;
        }
        #pragma unroll
        for (int r = 0; r < 4; r++) {
            float s = 0.f;
            #pragma unroll
            for (int a = 0; a < 32; a++) s += fmaxf(qv[r * 32 + a] + kk[a], 0.f) * w2v[a];
            s = fmaxf(s + b2, 0.f);
            size_t idx = (size_t)(row0 + r) * rs + (size_t)j * cs;
            float av = f32a ? ((const float*)adjv)[idx] : bf2f(((const u16*)adjv)[idx]);
            float e = __expf(s * av);
            outw[(size_t)(row0 + r) * 2048 + j] = f2bf(e);
            ls[r] += e;
        }
    }
    __syncthreads();
    #pragma unroll
    for (int r = 0; r < 4; r++) {
        red[tid] = ls[r]; __syncthreads();
        for (int o = 128; o > 0; o >>= 1) {
            if (tid < o) red[tid] += red[tid + o];
            __syncthreads();
        }
        if (tid == 0) rinv[row0 + r] = 1.f / red[0];
        __syncthreads();
    }
}

// ---------------- MFMA GEMM: C[.,coff:coff+128] = act(A @ BT^T * rowscale + bias)
__global__ __launch_bounds__(512) void gemm16(
    const void* __restrict__ A, int lda,
    const u16* __restrict__ BT, int ldb,
    u16* __restrict__ C, int ldc, int coff,
    int ksteps, const u16* __restrict__ bias,
    const float* __restrict__ rowscale, int act,
    const u32* __restrict__ flag, int araw) {
    int wave = threadIdx.x >> 6;
    int lane = threadIdx.x & 63;
    int m0 = blockIdx.x * 16;
    int mrow = lane & 15, quad = lane >> 4;
    bool af32 = araw && (flag[0] != 0);
    const u16*   ap  = (const u16*)A  + (size_t)(m0 + mrow) * lda + quad * 8;
    const float* afp = (const float*)A + (size_t)(m0 + mrow) * lda + quad * 8;
    const u16*   bp  = BT + (size_t)(wave * 16 + mrow) * ldb + quad * 8;
    f32x4 acc = {0.f, 0.f, 0.f, 0.f};
    for (int k = 0; k < ksteps; k++) {
        short8 a;
        if (af32) {
            float4 f0 = ((const float4*)afp)[0];
            float4 f1 = ((const float4*)afp)[1];
            a[0] = (short)f2bf(f0.x); a[1] = (short)f2bf(f0.y);
            a[2] = (short)f2bf(f0.z); a[3] = (short)f2bf(f0.w);
            a[4] = (short)f2bf(f1.x); a[5] = (short)f2bf(f1.y);
            a[6] = (short)f2bf(f1.z); a[7] = (short)f2bf(f1.w);
            afp += 32;
        } else {
            a = *(const short8*)ap;
            ap += 32;
        }
        short8 b = *(const short8*)bp;
        bp += 32;
        acc = __builtin_amdgcn_mfma_f32_16x16x32_bf16(a, b, acc, 0, 0, 0);
    }
    int col = wave * 16 + mrow;
    float bv = bias ? bf2f(bias[col]) : 0.f;
    #pragma unroll
    for (int r = 0; r < 4; r++) {
        int row = m0 + quad * 4 + r;
        float v = acc[r];
        if (rowscale) v *= rowscale[row];
        v += bv;
        if (act) v = seluf(v);
        C[(size_t)row * ldc + coff + col] = f2bf(v);
    }
}

// ---------------- pair gather: X[b,:] = h_e[di[b],:] * h_p[dr[b],:] ----------
__global__ __launch_bounds__(256) void xbuild(
    const u16* __restrict__ he, const u16* __restrict__ hp,
    const int* __restrict__ di, const int* __restrict__ dr, u16* __restrict__ X) {
    int idx = blockIdx.x * 256 + threadIdx.x;  // < B*64
    int d2 = idx & 63;
    int b = idx >> 6;
    int ia = di[b], ic = dr[b];
    u32 ue = ((const u32*)he)[ia * 64 + d2];
    u32 up = ((const u32*)hp)[ic * 64 + d2];
    float lo = bf2f((u16)(ue & 0xffff)) * bf2f((u16)(up & 0xffff));
    float hi = bf2f((u16)(ue >> 16)) * bf2f((u16)(up >> 16));
    ((u32*)X)[idx] = (u32)f2bf(lo) | ((u32)f2bf(hi) << 16);
}

// ---------------- z, sigmoid, per-block loss partials ----------------
// OUTPUT IS FLOAT32: out[0] = loss, out[1 + b] = sigmoid(z_b)
__global__ __launch_bounds__(256) void zloss(
    const u16* __restrict__ X2, const u16* __restrict__ wpred,
    const u16* __restrict__ bpred, const int* __restrict__ labels,
    float* __restrict__ out, float* __restrict__ part) {
    __shared__ float wp[128];
    __shared__ float ls[256];
    int tid = threadIdx.x;
    if (tid < 128) wp[tid] = bf2f(wpred[tid]);
    __syncthreads();
    int b = blockIdx.x * 256 + tid;
    const uint4* xp = (const uint4*)(X2 + (size_t)b * 128);
    float z = 0.f;
    #pragma unroll
    for (int i = 0; i < 16; i++) {
        uint4 q = xp[i];
        u32 u[4] = {q.x, q.y, q.z, q.w};
        #pragma unroll
        for (int c = 0; c < 4; c++) {
            z += bf2f((u16)(u[c] & 0xffff)) * wp[i * 8 + c * 2];
            z += bf2f((u16)(u[c] >> 16)) * wp[i * 8 + c * 2 + 1];
        }
    }
    z += bf2f(bpred[0]);
    out[1 + b] = 1.f / (1.f + __expf(-z));
    float y = (float)labels[b];
    ls[tid] = fmaxf(z, 0.f) - z * y + log1pf(__expf(-fabsf(z)));
    __syncthreads();
    for (int o = 128; o > 0; o >>= 1) {
        if (tid < o) ls[tid] += ls[tid + o];
        __syncthreads();
    }
    if (tid == 0) part[blockIdx.x] = ls[0];
}

__global__ void finloss(const float* __restrict__ part, float* __restrict__ out) {
    __shared__ float s[64];
    s[threadIdx.x] = part[threadIdx.x];
    __syncthreads();
    for (int o = 32; o > 0; o >>= 1) {
        if (threadIdx.x < o) s[threadIdx.x] += s[threadIdx.x + o];
        __syncthreads();
    }
    if (threadIdx.x == 0) out[0] = s[0] * (1.f / 16384.f);
}

// ---------------- launch ----------------
extern "C" void kernel_launch(void* const* d_in, const int* in_sizes, int n_in,
                              void* d_out, int out_size, void* d_ws, size_t ws_size,
                              hipStream_t stream) {
    const void* e_p_adj = d_in[0];
    const void* e_e_adj = d_in[1];
    const void* p_p_adj = d_in[2];
    const int* in_dis  = (const int*)d_in[3];
    const int* in_drug = (const int*)d_in[4];
    const int* labels  = (const int*)d_in[5];
    float* out = (float*)d_out;

    // -------- workspace layout (~15.3 MB) --------
    char* ws = (char*)d_ws;
    size_t off = 0;
    auto take = [&](size_t bytes) { char* p = ws + off; off = (off + bytes + 255) & ~(size_t)255; return p; };
    u16*   Wbuf  = (u16*)take((size_t)2048 * 2048 * 2);   // exp weights; later X(4MB)+X1(4MB)
    u16*   drugT = (u16*)take((size_t)128 * 2048 * 2);    // --- X2 overlays drugT..A_p (4 MB) ---
    u16*   disT  = (u16*)take((size_t)128 * 2048 * 2);
    float* ko_d  = (float*)take((size_t)2048 * 32 * 4);
    float* qs_d  = (float*)take((size_t)2048 * 32 * 4);
    float* ko_p  = (float*)take((size_t)2048 * 32 * 4);
    float* qs_p  = (float*)take((size_t)2048 * 32 * 4);
    u16*   A_e   = (u16*)take((size_t)2048 * 256 * 2);
    u16*   A_p   = (u16*)take((size_t)2048 * 256 * 2);
    u16*   WcTe  = (u16*)take((size_t)128 * 256 * 2);
    u16*   WcTp  = (u16*)take((size_t)128 * 256 * 2);
    u16*   W1T   = (u16*)take((size_t)128 * 128 * 2);
    u16*   W2T   = (u16*)take((size_t)128 * 128 * 2);
    u16*   b_e   = (u16*)take(256);
    u16*   b_p   = (u16*)take(256);
    u16*   h_e   = (u16*)take((size_t)2048 * 128 * 2);
    u16*   h_p   = (u16*)take((size_t)2048 * 128 * 2);
    float* dinv_e = (float*)take(2048 * 4);
    float* dinv_p = (float*)take(2048 * 4);
    float* rinv   = (float*)take(2048 * 4);
    float* part  = (float*)take(64 * 4);
    u16*   canon = (u16*)take((size_t)700000 * 2);        // canonical bf16 params
    u32*   flag  = (u32*)take(256);
    // aliases (lifetimes disjoint)
    u16* X  = Wbuf;                           // [B,128] bf16 (4 MB)
    u16* X1 = Wbuf + (size_t)BB * 128;        // next 4 MB
    u16* X2 = drugT;                          // exactly 4 MB over drugT..A_p

    // -------- canonical parameter table --------
    const int segidx[NSEG] = {6, 7, 14, 18, 8, 22, 11, 24, 26, 28,
                              15, 16, 17, 19, 20, 21,
                              9, 10, 12, 13, 23, 25, 27, 29, 30, 31};
    const int segn[NSEG]   = {262144, 262144, 8192, 8192, 16384, 16384, 16384, 16384, 16384, 16384,
                              32, 32, 1, 32, 32, 1,
                              128, 128, 128, 128, 128, 128, 128, 128, 128, 1};
    CvtArgs ca;
    u16* cp[NSEG];
    {
        int o = 0;
        for (int i = 0; i < NSEG; i++) {
            ca.src[i] = d_in[segidx[i]];
            ca.off[i] = o;
            ca.n[i] = segn[i];
            cp[i] = canon + o;
            o += (segn[i] + 15) & ~15;
        }
    }
    u16 *cdemb = cp[0], *cpemb = cp[1], *cWa1d = cp[2], *cWa1p = cp[3];
    u16 *cWdg = cp[4], *cWd2 = cp[5], *cWpg = cp[6], *cWp3 = cp[7];
    u16 *cW1 = cp[8], *cW2 = cp[9];
    u16 *cba1d = cp[10], *cWa2d = cp[11], *cba2d = cp[12];
    u16 *cba1p = cp[13], *cWa2p = cp[14], *cba2p = cp[15];
    u16 *cbdg_lin = cp[16], *cbdg = cp[17], *cbpg_lin = cp[18], *cbpg = cp[19];
    u16 *cbd2 = cp[20], *cbp3 = cp[21], *cmb1 = cp[22], *cmb2 = cp[23];
    u16 *cWpred = cp[24], *cbpred = cp[25];

    // -------- 0. dtype detection + canonicalization --------
    detectk<<<1, 256, 0, stream>>>(d_in[6], flag);
    cvtk<<<dim3(64, NSEG), 256, 0, stream>>>(ca, canon, flag);

    // -------- 1. prep: transposes, biases, degrees, projections --------
    tpose_embs<<<dim3(4, 64, 2), dim3(32, 8), 0, stream>>>(cdemb, cpemb, disT, drugT);
    tpose_smalls<<<dim3(4, 4, 6), dim3(32, 8), 0, stream>>>(
        cW1, cW2, cWdg, cWd2, cWpg, cWp3, W1T, W2T, WcTe, WcTp);
    biasc<<<1, 128, 0, stream>>>(cbdg_lin, cbdg, cbd2, b_e, cbpg_lin, cbpg, cbp3, b_p);
    degk<<<dim3(2048, 2), 256, 0, stream>>>(e_e_adj, dinv_e, p_p_adj, dinv_p, flag);
    koqs<<<dim3(2048, 4), 128, 0, stream>>>(cdemb, cpemb, cWa1d, cba1d, cWa1p, cba1p,
                                            ko_d, qs_d, ko_p, qs_p);

    // -------- 2. disease-side attention + aggregation (softmax via rowscale) --------
    attnw2<<<512, 256, 0, stream>>>(qs_d, ko_d, e_p_adj, 2048, 1, cWa2d, cba2d,
                                    Wbuf, rinv, flag);
    gemm16<<<128, 512, 0, stream>>>(Wbuf, 2048, drugT, 2048, A_e, 256, 0, 64,
                                    nullptr, rinv, 0, flag, 0);

    // -------- 3. drug-side attention (adj read transposed) + aggregation --------
    attnw2<<<512, 256, 0, stream>>>(qs_p, ko_p, e_p_adj, 1, 2048, cWa2p, cba2p,
                                    Wbuf, rinv, flag);
    gemm16<<<128, 512, 0, stream>>>(Wbuf, 2048, disT, 2048, A_p, 256, 0, 64,
                                    nullptr, rinv, 0, flag, 0);

    // -------- 4. knn branches: raw adjacency GEMM with 1/deg row-scale --------
    gemm16<<<128, 512, 0, stream>>>(e_e_adj, 2048, disT, 2048, A_e, 256, 128, 64,
                                    nullptr, dinv_e, 0, flag, 1);
    gemm16<<<128, 512, 0, stream>>>(p_p_adj, 2048, drugT, 2048, A_p, 256, 128, 64,
                                    nullptr, dinv_p, 0, flag, 1);

    // -------- 5. combine GEMMs with bias + SELU --------
    gemm16<<<128, 512, 0, stream>>>(A_e, 256, WcTe, 256, h_e, 128, 0, 8, b_e,
                                    nullptr, 1, flag, 0);
    gemm16<<<128, 512, 0, stream>>>(A_p, 256, WcTp, 256, h_p, 128, 0, 8, b_p,
                                    nullptr, 1, flag, 0);

    // -------- 6. pair MLP --------
    xbuild<<<4096, 256, 0, stream>>>(h_e, h_p, in_dis, in_drug, X);
    gemm16<<<1024, 512, 0, stream>>>(X, 128, W1T, 128, X1, 128, 0, 4, cmb1,
                                     nullptr, 1, flag, 0);
    gemm16<<<1024, 512, 0, stream>>>(X1, 128, W2T, 128, X2, 128, 0, 4, cmb2,
                                     nullptr, 1, flag, 0);

    // -------- 7. z / sigmoid / loss (float32 output: loss first) --------
    zloss<<<64, 256, 0, stream>>>(X2, cWpred, cbpred, labels, out, part);
    finloss<<<1, 64, 0, stream>>>(part, out);
}

// Round 7
// 407.725 us; speedup vs baseline: 1.0975x; 1.0975x over previous
//
#include <hip/hip_runtime.h>

#define ND   2048
#define BB   16384

typedef unsigned short u16;
typedef unsigned int u32;
typedef __attribute__((ext_vector_type(8))) short short8;
typedef __attribute__((ext_vector_type(4))) float f32x4;

__device__ inline float bf2f(u16 u) {
    union { u32 i; float f; } v; v.i = ((u32)u) << 16; return v.f;
}
__device__ inline u16 f2bf(float f) {
    union { float f; u32 i; } v; v.f = f;
    u32 i = v.i + 0x7fffu + ((v.i >> 16) & 1u);
    return (u16)(i >> 16);
}
__device__ inline float seluf(float x) {
    const float sc = 1.0507009873554805f, al = 1.6732632423543772f;
    return x > 0.f ? sc * x : sc * al * expm1f(x);
}
__device__ inline short8 packbf8(float4 f0, float4 f1) {
    short8 a;
    a[0] = (short)f2bf(f0.x); a[1] = (short)f2bf(f0.y);
    a[2] = (short)f2bf(f0.z); a[3] = (short)f2bf(f0.w);
    a[4] = (short)f2bf(f1.x); a[5] = (short)f2bf(f1.y);
    a[6] = (short)f2bf(f1.z); a[7] = (short)f2bf(f1.w);
    return a;
}

// ---------------- dtype sniffer ----------------
__global__ void detectk(const void* __restrict__ demb, u32* __restrict__ flag) {
    const u16* p = (const u16*)demb;
    int tid = threadIdx.x;  // 256
    int sane = 0;
    #pragma unroll
    for (int i = 0; i < 2; i++) {
        u16 u = p[4 * tid + 2 * i];
        int e = (u >> 7) & 0xFF;
        if (u == 0 || (e >= 0x66 && e <= 0x8C)) sane++;
    }
    __shared__ int red[256];
    red[tid] = sane; __syncthreads();
    for (int o = 128; o > 0; o >>= 1) {
        if (tid < o) red[tid] += red[tid + o];
        __syncthreads();
    }
    if (tid == 0) flag[0] = (red[0] < 300) ? 1u : 0u;
}

// ---------------- canonical bf16 conversion (26 segments, one launch) -------
#define NSEG 26
struct CvtArgs { const void* src[NSEG]; int off[NSEG]; int n[NSEG]; };

__global__ __launch_bounds__(256) void cvtk(CvtArgs a, u16* __restrict__ base,
                                            const u32* __restrict__ flag) {
    int seg = blockIdx.y;
    int n = a.n[seg];
    const void* s = a.src[seg];
    u16* d = base + a.off[seg];
    bool f32 = flag[0] != 0;
    int stride = gridDim.x * blockDim.x;
    for (int i = blockIdx.x * blockDim.x + threadIdx.x; i < n; i += stride)
        d[i] = f32 ? f2bf(((const float*)s)[i]) : ((const u16*)s)[i];
}

// ---------------- transpose (bf16, tiled 32x32) ----------------
__device__ inline void tpose_body(const u16* in, int R, int C,
                                  u16* out, int ldo, int ooff,
                                  u16 (*tile)[33]) {
    int c0 = blockIdx.x * 32, r0 = blockIdx.y * 32;
    int x = c0 + threadIdx.x;
    for (int i = threadIdx.y; i < 32; i += 8) {
        int r = r0 + i;
        tile[i][threadIdx.x] = (r < R && x < C) ? in[(size_t)r * C + x] : (u16)0;
    }
    __syncthreads();
    int rr = r0 + threadIdx.x;
    for (int i = threadIdx.y; i < 32; i += 8) {
        int cc = c0 + i;
        if (cc < C && rr < R) out[(size_t)cc * ldo + ooff + rr] = tile[threadIdx.x][i];
    }
}

__global__ void tpose_embs(const u16* __restrict__ demb, const u16* __restrict__ pemb,
                           u16* __restrict__ disT, u16* __restrict__ drugT) {
    __shared__ u16 tile[32][33];
    if (blockIdx.z == 0) tpose_body(demb, ND, 128, disT, ND, 0, tile);
    else                 tpose_body(pemb, ND, 128, drugT, ND, 0, tile);
}

__global__ void tpose_smalls(const u16* s0, const u16* s1, const u16* s2,
                             const u16* s3, const u16* s4, const u16* s5,
                             u16* W1T, u16* W2T, u16* WcTe, u16* WcTp) {
    __shared__ u16 tile[32][33];
    const u16* in; u16* out; int ldo, ooff;
    switch (blockIdx.z) {
        case 0:  in = s0; out = W1T;  ldo = 128; ooff = 0;   break;
        case 1:  in = s1; out = W2T;  ldo = 128; ooff = 0;   break;
        case 2:  in = s2; out = WcTe; ldo = 256; ooff = 0;   break;
        case 3:  in = s3; out = WcTe; ldo = 256; ooff = 128; break;
        case 4:  in = s4; out = WcTp; ldo = 256; ooff = 0;   break;
        default: in = s5; out = WcTp; ldo = 256; ooff = 128; break;
    }
    tpose_body(in, 128, 128, out, ldo, ooff, tile);
}

// ---------------- combined biases ----------------
__global__ void biasc(const u16* a0, const u16* a1, const u16* a2, u16* o0,
                      const u16* b0, const u16* b1, const u16* b2, u16* o1) {
    int t = threadIdx.x;  // 128
    o0[t] = f2bf(bf2f(a0[t]) + bf2f(a1[t]) + bf2f(a2[t]));
    o1[t] = f2bf(bf2f(b0[t]) + bf2f(b1[t]) + bf2f(b2[t]));
}

// ---------------- inverse degree ----------------
__global__ __launch_bounds__(256) void degk(
    const void* __restrict__ e_e, float* __restrict__ dinv_e,
    const void* __restrict__ p_p, float* __restrict__ dinv_p,
    const u32* __restrict__ flag) {
    int row = blockIdx.x, tid = threadIdx.x;
    const void* ab = blockIdx.y ? p_p : e_e;
    float* o = blockIdx.y ? dinv_p : dinv_e;
    bool f32 = flag[0] != 0;
    float s = 0.f;
    if (f32) {
        const float4* a4 = (const float4*)((const float*)ab + (size_t)row * 2048) + tid * 2;
        float4 v0 = a4[0], v1 = a4[1];
        s = v0.x + v0.y + v0.z + v0.w + v1.x + v1.y + v1.z + v1.w;
    } else {
        const uint4* a4 = (const uint4*)((const u16*)ab + (size_t)row * 2048) + tid;
        uint4 v = a4[0];
        u32 u[4] = {v.x, v.y, v.z, v.w};
        #pragma unroll
        for (int c = 0; c < 4; c++)
            s += bf2f((u16)(u[c] & 0xffff)) + bf2f((u16)(u[c] >> 16));
    }
    __shared__ float red[256];
    red[tid] = s; __syncthreads();
    for (int ofs = 128; ofs > 0; ofs >>= 1) {
        if (tid < ofs) red[tid] += red[tid + ofs];
        __syncthreads();
    }
    if (tid == 0) o[row] = 1.f / (red[0] + 1e-8f);
}

// ---------------- ko / qs projections ----------
__global__ __launch_bounds__(128) void koqs(
    const u16* __restrict__ demb, const u16* __restrict__ pemb,
    const u16* __restrict__ Wa1d, const u16* __restrict__ ba1d,
    const u16* __restrict__ Wa1p, const u16* __restrict__ ba1p,
    float* __restrict__ ko_d, float* __restrict__ qs_d,
    float* __restrict__ ko_p, float* __restrict__ qs_p) {
    int row = blockIdx.x, m = blockIdx.y, tid = threadIdx.x;
    const u16* src; const u16* W; const u16* bias; float* out;
    switch (m) {
        case 0:  src = pemb; W = Wa1d;            bias = nullptr; out = ko_d; break;
        case 1:  src = demb; W = Wa1d + 128 * 32; bias = ba1d;    out = qs_d; break;
        case 2:  src = demb; W = Wa1p;            bias = nullptr; out = ko_p; break;
        default: src = pemb; W = Wa1p + 128 * 32; bias = ba1p;    out = qs_p; break;
    }
    __shared__ float x[128];
    __shared__ float red[128];
    x[tid] = bf2f(src[(size_t)row * 128 + tid]);
    __syncthreads();
    int a = tid & 31, part = tid >> 5;
    float s = 0.f;
    #pragma unroll
    for (int k = 0; k < 32; k++) s += x[part * 32 + k] * bf2f(W[(part * 32 + k) * 32 + a]);
    red[tid] = s;
    __syncthreads();
    if (part == 0) {
        float t = red[a] + red[a + 32] + red[a + 64] + red[a + 96];
        if (bias) t += bf2f(bias[a]);
        out[(size_t)row * 32 + a] = t;
    }
}

// ---------------- attention: coalesced, LDS-tiled adjacency ----------------
// 8 rows per block, 256 threads. Writes exp weights + per-row inverse sums.
__global__ __launch_bounds__(256) void attnw3(
    const float* __restrict__ qs, const float* __restrict__ ko,
    const void* __restrict__ adjv, int transposed,
    const u16* __restrict__ w2, const u16* __restrict__ b2p,
    u16* __restrict__ outw, float* __restrict__ rinv,
    const u32* __restrict__ flag) {
    __shared__ float tile[256][9];
    __shared__ float qv[8][32];
    __shared__ float w2v[32];
    __shared__ float partial[4][8];
    int tid = threadIdx.x;
    int row0 = blockIdx.x * 8;
    bool f32a = flag[0] != 0;
    { int r = tid >> 5, a = tid & 31; qv[r][a] = qs[(size_t)(row0 + r) * 32 + a]; }
    if (tid < 32) w2v[tid] = bf2f(w2[tid]);
    __syncthreads();
    float b2 = bf2f(b2p[0]);
    float ls[8] = {0.f, 0.f, 0.f, 0.f, 0.f, 0.f, 0.f, 0.f};
    for (int c = 0; c < 8; c++) {
        int j0 = c * 256;
        // stage tile[t][r] = adj(row0+r, j0+t)
        if (transposed) {
            if (f32a) {
                const float4* src = (const float4*)((const float*)adjv +
                                    (size_t)(j0 + tid) * 2048 + row0);
                float4 v0 = src[0], v1 = src[1];
                tile[tid][0] = v0.x; tile[tid][1] = v0.y; tile[tid][2] = v0.z; tile[tid][3] = v0.w;
                tile[tid][4] = v1.x; tile[tid][5] = v1.y; tile[tid][6] = v1.z; tile[tid][7] = v1.w;
            } else {
                const uint4* src = (const uint4*)((const u16*)adjv +
                                   (size_t)(j0 + tid) * 2048 + row0);
                uint4 v = src[0];
                u32 u[4] = {v.x, v.y, v.z, v.w};
                #pragma unroll
                for (int q = 0; q < 4; q++) {
                    tile[tid][q * 2]     = bf2f((u16)(u[q] & 0xffff));
                    tile[tid][q * 2 + 1] = bf2f((u16)(u[q] >> 16));
                }
            }
        } else {
            #pragma unroll
            for (int r = 0; r < 8; r++) {
                size_t idx = (size_t)(row0 + r) * 2048 + j0 + tid;
                tile[tid][r] = f32a ? ((const float*)adjv)[idx]
                                    : bf2f(((const u16*)adjv)[idx]);
            }
        }
        __syncthreads();
        // compute: this thread's j = j0 + tid
        float kk[32];
        const float4* kp = (const float4*)(ko + (size_t)(j0 + tid) * 32);
        #pragma unroll
        for (int q = 0; q < 8; q++) {
            float4 v = kp[q];
            kk[q * 4] = v.x; kk[q * 4 + 1] = v.y; kk[q * 4 + 2] = v.z; kk[q * 4 + 3] = v.w;
        }
        #pragma unroll
        for (int r = 0; r < 8; r++) {
            float s = 0.f;
            #pragma unroll
            for (int a = 0; a < 32; a++) s += fmaxf(qv[r][a] + kk[a], 0.f) * w2v[a];
            s = fmaxf(s + b2, 0.f);
            float e = __expf(s * tile[tid][r]);
            outw[(size_t)(row0 + r) * 2048 + j0 + tid] = f2bf(e);
            ls[r] += e;
        }
        __syncthreads();
    }
    int lane = tid & 63, wv = tid >> 6;
    #pragma unroll
    for (int r = 0; r < 8; r++) {
        float v = ls[r];
        #pragma unroll
        for (int o = 32; o > 0; o >>= 1) v += __shfl_down(v, o, 64);
        if (lane == 0) partial[wv][r] = v;
    }
    __syncthreads();
    if (tid < 8)
        rinv[row0 + tid] = 1.f / (partial[0][tid] + partial[1][tid] +
                                  partial[2][tid] + partial[3][tid]);
}

// ---------------- MFMA GEMM, software-pipelined, z-batched (2 descs) --------
// block 256 thr (4 waves). Block tile: 16 rows x 128 cols; wave w owns cols
// [w*32, w*32+32) as two 16x16 accumulators (2 independent MFMA chains).
struct GD {
    const void* A[2]; const u16* BT[2]; u16* C[2];
    const u16* bias[2]; const float* rowscale[2];
    int lda[2], ldb[2], ldc[2], coff[2], ksteps[2], act[2], araw[2];
};

__global__ __launch_bounds__(256) void gemm16b(GD g, const u32* __restrict__ flag) {
    int z = blockIdx.y;
    bool af32 = g.araw[z] && (flag[0] != 0);
    const u16*   A16 = (const u16*)g.A[z];
    const float* A32 = (const float*)g.A[z];
    int lda = g.lda[z], ldb = g.ldb[z];
    int tid = threadIdx.x;
    int lane = tid & 63, wv = tid >> 6;
    int mrow = lane & 15, quad = lane >> 4;
    int m0 = blockIdx.x * 16;
    int c0 = wv * 32;
    size_t aoff = (size_t)(m0 + mrow) * lda + quad * 8;
    const u16* b0p = g.BT[z] + (size_t)(c0 + mrow) * ldb + quad * 8;
    const u16* b1p = g.BT[z] + (size_t)(c0 + 16 + mrow) * ldb + quad * 8;
    f32x4 acc0 = {0.f, 0.f, 0.f, 0.f}, acc1 = {0.f, 0.f, 0.f, 0.f};
    int ks = g.ksteps[z];

    auto aload = [&](int k) -> short8 {
        if (af32) {
            const float4* p = (const float4*)(A32 + aoff + (size_t)k * 32);
            return packbf8(p[0], p[1]);
        }
        return *(const short8*)(A16 + aoff + (size_t)k * 32);
    };
    short8 ac  = aload(0);
    short8 b0c = *(const short8*)b0p;
    short8 b1c = *(const short8*)b1p;
    #pragma unroll 2
    for (int k = 1; k < ks; k++) {
        short8 an  = aload(k);
        short8 b0n = *(const short8*)(b0p + (size_t)k * 32);
        short8 b1n = *(const short8*)(b1p + (size_t)k * 32);
        acc0 = __builtin_amdgcn_mfma_f32_16x16x32_bf16(ac, b0c, acc0, 0, 0, 0);
        acc1 = __builtin_amdgcn_mfma_f32_16x16x32_bf16(ac, b1c, acc1, 0, 0, 0);
        ac = an; b0c = b0n; b1c = b1n;
    }
    acc0 = __builtin_amdgcn_mfma_f32_16x16x32_bf16(ac, b0c, acc0, 0, 0, 0);
    acc1 = __builtin_amdgcn_mfma_f32_16x16x32_bf16(ac, b1c, acc1, 0, 0, 0);

    const float* rs = g.rowscale[z];
    const u16* bi = g.bias[z];
    u16* C = g.C[z];
    int ldc = g.ldc[z], coff = g.coff[z], act = g.act[z];
    int n0 = c0 + mrow, n1 = n0 + 16;
    float bv0 = bi ? bf2f(bi[n0]) : 0.f;
    float bv1 = bi ? bf2f(bi[n1]) : 0.f;
    #pragma unroll
    for (int r = 0; r < 4; r++) {
        int row = m0 + quad * 4 + r;
        float v0 = acc0[r], v1 = acc1[r];
        if (rs) { float sc = rs[row]; v0 *= sc; v1 *= sc; }
        v0 += bv0; v1 += bv1;
        if (act) { v0 = seluf(v0); v1 = seluf(v1); }
        C[(size_t)row * ldc + coff + n0] = f2bf(v0);
        C[(size_t)row * ldc + coff + n1] = f2bf(v1);
    }
}

// ---------------- pair gather ----------
__global__ __launch_bounds__(256) void xbuild(
    const u16* __restrict__ he, const u16* __restrict__ hp,
    const int* __restrict__ di, const int* __restrict__ dr, u16* __restrict__ X) {
    int idx = blockIdx.x * 256 + threadIdx.x;  // < B*64
    int d2 = idx & 63;
    int b = idx >> 6;
    int ia = di[b], ic = dr[b];
    u32 ue = ((const u32*)he)[ia * 64 + d2];
    u32 up = ((const u32*)hp)[ic * 64 + d2];
    float lo = bf2f((u16)(ue & 0xffff)) * bf2f((u16)(up & 0xffff));
    float hi = bf2f((u16)(ue >> 16)) * bf2f((u16)(up >> 16));
    ((u32*)X)[idx] = (u32)f2bf(lo) | ((u32)f2bf(hi) << 16);
}

// ---------------- z, sigmoid, loss (FLOAT32 out: out[0]=loss, out[1+b]=sig) --
__global__ __launch_bounds__(256) void zloss(
    const u16* __restrict__ X2, const u16* __restrict__ wpred,
    const u16* __restrict__ bpred, const int* __restrict__ labels,
    float* __restrict__ out, float* __restrict__ part) {
    __shared__ float wp[128];
    __shared__ float ls[256];
    int tid = threadIdx.x;
    if (tid < 128) wp[tid] = bf2f(wpred[tid]);
    __syncthreads();
    int b = blockIdx.x * 256 + tid;
    const uint4* xp = (const uint4*)(X2 + (size_t)b * 128);
    float z = 0.f;
    #pragma unroll
    for (int i = 0; i < 16; i++) {
        uint4 q = xp[i];
        u32 u[4] = {q.x, q.y, q.z, q.w};
        #pragma unroll
        for (int c = 0; c < 4; c++) {
            z += bf2f((u16)(u[c] & 0xffff)) * wp[i * 8 + c * 2];
            z += bf2f((u16)(u[c] >> 16)) * wp[i * 8 + c * 2 + 1];
        }
    }
    z += bf2f(bpred[0]);
    out[1 + b] = 1.f / (1.f + __expf(-z));
    float y = (float)labels[b];
    ls[tid] = fmaxf(z, 0.f) - z * y + log1pf(__expf(-fabsf(z)));
    __syncthreads();
    for (int o = 128; o > 0; o >>= 1) {
        if (tid < o) ls[tid] += ls[tid + o];
        __syncthreads();
    }
    if (tid == 0) part[blockIdx.x] = ls[0];
}

__global__ void finloss(const float* __restrict__ part, float* __restrict__ out) {
    __shared__ float s[64];
    s[threadIdx.x] = part[threadIdx.x];
    __syncthreads();
    for (int o = 32; o > 0; o >>= 1) {
        if (threadIdx.x < o) s[threadIdx.x] += s[threadIdx.x + o];
        __syncthreads();
    }
    if (threadIdx.x == 0) out[0] = s[0] * (1.f / 16384.f);
}

// ---------------- launch ----------------
extern "C" void kernel_launch(void* const* d_in, const int* in_sizes, int n_in,
                              void* d_out, int out_size, void* d_ws, size_t ws_size,
                              hipStream_t stream) {
    const void* e_p_adj = d_in[0];
    const void* e_e_adj = d_in[1];
    const void* p_p_adj = d_in[2];
    const int* in_dis  = (const int*)d_in[3];
    const int* in_drug = (const int*)d_in[4];
    const int* labels  = (const int*)d_in[5];
    float* out = (float*)d_out;

    // -------- workspace layout (~15.4 MB) --------
    char* ws = (char*)d_ws;
    size_t off = 0;
    auto take = [&](size_t bytes) { char* p = ws + off; off = (off + bytes + 255) & ~(size_t)255; return p; };
    u16*   Wbuf  = (u16*)take((size_t)2048 * 2048 * 2);   // exp weights; later X+X1
    u16*   drugT = (u16*)take((size_t)128 * 2048 * 2);    // --- X2 overlays drugT..A_p ---
    u16*   disT  = (u16*)take((size_t)128 * 2048 * 2);
    float* ko_d  = (float*)take((size_t)2048 * 32 * 4);
    float* qs_d  = (float*)take((size_t)2048 * 32 * 4);
    float* ko_p  = (float*)take((size_t)2048 * 32 * 4);
    float* qs_p  = (float*)take((size_t)2048 * 32 * 4);
    u16*   A_e   = (u16*)take((size_t)2048 * 256 * 2);
    u16*   A_p   = (u16*)take((size_t)2048 * 256 * 2);
    u16*   WcTe  = (u16*)take((size_t)128 * 256 * 2);
    u16*   WcTp  = (u16*)take((size_t)128 * 256 * 2);
    u16*   W1T   = (u16*)take((size_t)128 * 128 * 2);
    u16*   W2T   = (u16*)take((size_t)128 * 128 * 2);
    u16*   b_e   = (u16*)take(256);
    u16*   b_p   = (u16*)take(256);
    u16*   h_e   = (u16*)take((size_t)2048 * 128 * 2);
    u16*   h_p   = (u16*)take((size_t)2048 * 128 * 2);
    float* dinv_e = (float*)take(2048 * 4);
    float* dinv_p = (float*)take(2048 * 4);
    float* rinvD  = (float*)take(2048 * 4);
    float* rinvP  = (float*)take(2048 * 4);
    float* part  = (float*)take(64 * 4);
    u16*   canon = (u16*)take((size_t)700000 * 2);
    u32*   flag  = (u32*)take(256);
    u16* X  = Wbuf;
    u16* X1 = Wbuf + (size_t)BB * 128;
    u16* X2 = drugT;   // 4 MB over drugT..A_p

    // -------- canonical parameter table --------
    const int segidx[NSEG] = {6, 7, 14, 18, 8, 22, 11, 24, 26, 28,
                              15, 16, 17, 19, 20, 21,
                              9, 10, 12, 13, 23, 25, 27, 29, 30, 31};
    const int segn[NSEG]   = {262144, 262144, 8192, 8192, 16384, 16384, 16384, 16384, 16384, 16384,
                              32, 32, 1, 32, 32, 1,
                              128, 128, 128, 128, 128, 128, 128, 128, 128, 1};
    CvtArgs ca;
    u16* cp[NSEG];
    {
        int o = 0;
        for (int i = 0; i < NSEG; i++) {
            ca.src[i] = d_in[segidx[i]];
            ca.off[i] = o;
            ca.n[i] = segn[i];
            cp[i] = canon + o;
            o += (segn[i] + 15) & ~15;
        }
    }
    u16 *cdemb = cp[0], *cpemb = cp[1], *cWa1d = cp[2], *cWa1p = cp[3];
    u16 *cWdg = cp[4], *cWd2 = cp[5], *cWpg = cp[6], *cWp3 = cp[7];
    u16 *cW1 = cp[8], *cW2 = cp[9];
    u16 *cba1d = cp[10], *cWa2d = cp[11], *cba2d = cp[12];
    u16 *cba1p = cp[13], *cWa2p = cp[14], *cba2p = cp[15];
    u16 *cbdg_lin = cp[16], *cbdg = cp[17], *cbpg_lin = cp[18], *cbpg = cp[19];
    u16 *cbd2 = cp[20], *cbp3 = cp[21], *cmb1 = cp[22], *cmb2 = cp[23];
    u16 *cWpred = cp[24], *cbpred = cp[25];

    // -------- 0. dtype detection + canonicalization --------
    detectk<<<1, 256, 0, stream>>>(d_in[6], flag);
    cvtk<<<dim3(64, NSEG), 256, 0, stream>>>(ca, canon, flag);

    // -------- 1. prep --------
    tpose_embs<<<dim3(4, 64, 2), dim3(32, 8), 0, stream>>>(cdemb, cpemb, disT, drugT);
    tpose_smalls<<<dim3(4, 4, 6), dim3(32, 8), 0, stream>>>(
        cW1, cW2, cWdg, cWd2, cWpg, cWp3, W1T, W2T, WcTe, WcTp);
    biasc<<<1, 128, 0, stream>>>(cbdg_lin, cbdg, cbd2, b_e, cbpg_lin, cbpg, cbp3, b_p);
    degk<<<dim3(2048, 2), 256, 0, stream>>>(e_e_adj, dinv_e, p_p_adj, dinv_p, flag);
    koqs<<<dim3(2048, 4), 128, 0, stream>>>(cdemb, cpemb, cWa1d, cba1d, cWa1p, cba1p,
                                            ko_d, qs_d, ko_p, qs_p);

    auto mkgd = [](const void* A0, int lda0, const u16* BT0, int ldb0, u16* C0,
                   int ldc0, int coff0, int ks0, const u16* bi0, const float* rs0,
                   int act0, int araw0,
                   const void* A1, int lda1, const u16* BT1, int ldb1, u16* C1,
                   int ldc1, int coff1, int ks1, const u16* bi1, const float* rs1,
                   int act1, int araw1) {
        GD g;
        g.A[0] = A0; g.lda[0] = lda0; g.BT[0] = BT0; g.ldb[0] = ldb0;
        g.C[0] = C0; g.ldc[0] = ldc0; g.coff[0] = coff0; g.ksteps[0] = ks0;
        g.bias[0] = bi0; g.rowscale[0] = rs0; g.act[0] = act0; g.araw[0] = araw0;
        g.A[1] = A1; g.lda[1] = lda1; g.BT[1] = BT1; g.ldb[1] = ldb1;
        g.C[1] = C1; g.ldc[1] = ldc1; g.coff[1] = coff1; g.ksteps[1] = ks1;
        g.bias[1] = bi1; g.rowscale[1] = rs1; g.act[1] = act1; g.araw[1] = araw1;
        return g;
    };

    // -------- 2. disease-side attention, then {att-agg, knn-agg} batch ------
    attnw3<<<256, 256, 0, stream>>>(qs_d, ko_d, e_p_adj, 0, cWa2d, cba2d,
                                    Wbuf, rinvD, flag);
    {
        GD g = mkgd(Wbuf, 2048, drugT, 2048, A_e, 256, 0, 64, nullptr, rinvD, 0, 0,
                    e_e_adj, 2048, disT, 2048, A_e, 256, 128, 64, nullptr, dinv_e, 0, 1);
        gemm16b<<<dim3(128, 2), 256, 0, stream>>>(g, flag);
    }

    // -------- 3. drug-side attention (transposed adj), then batch ----------
    attnw3<<<256, 256, 0, stream>>>(qs_p, ko_p, e_p_adj, 1, cWa2p, cba2p,
                                    Wbuf, rinvP, flag);
    {
        GD g = mkgd(Wbuf, 2048, disT, 2048, A_p, 256, 0, 64, nullptr, rinvP, 0, 0,
                    p_p_adj, 2048, drugT, 2048, A_p, 256, 128, 64, nullptr, dinv_p, 0, 1);
        gemm16b<<<dim3(128, 2), 256, 0, stream>>>(g, flag);
    }

    // -------- 4. combine GEMMs (bias + SELU), batched ----------------------
    {
        GD g = mkgd(A_e, 256, WcTe, 256, h_e, 128, 0, 8, b_e, nullptr, 1, 0,
                    A_p, 256, WcTp, 256, h_p, 128, 0, 8, b_p, nullptr, 1, 0);
        gemm16b<<<dim3(128, 2), 256, 0, stream>>>(g, flag);
    }

    // -------- 5. pair MLP --------
    xbuild<<<4096, 256, 0, stream>>>(h_e, h_p, in_dis, in_drug, X);
    {
        GD g = mkgd(X, 128, W1T, 128, X1, 128, 0, 4, cmb1, nullptr, 1, 0,
                    X, 128, W1T, 128, X1, 128, 0, 4, cmb1, nullptr, 1, 0);
        gemm16b<<<dim3(1024, 1), 256, 0, stream>>>(g, flag);
    }
    {
        GD g = mkgd(X1, 128, W2T, 128, X2, 128, 0, 4, cmb2, nullptr, 1, 0,
                    X1, 128, W2T, 128, X2, 128, 0, 4, cmb2, nullptr, 1, 0);
        gemm16b<<<dim3(1024, 1), 256, 0, stream>>>(g, flag);
    }

    // -------- 6. z / sigmoid / loss --------
    zloss<<<64, 256, 0, stream>>>(X2, cWpred, cbpred, labels, out, part);
    finloss<<<1, 64, 0, stream>>>(part, out);
}

// Round 8
// 407.022 us; speedup vs baseline: 1.0993x; 1.0017x over previous
//
#include <hip/hip_runtime.h>

#define ND   2048
#define BB   16384

typedef unsigned short u16;
typedef unsigned int u32;
typedef __attribute__((ext_vector_type(8))) short short8;
typedef __attribute__((ext_vector_type(4))) float f32x4;

__device__ inline float bf2f(u16 u) {
    union { u32 i; float f; } v; v.i = ((u32)u) << 16; return v.f;
}
__device__ inline u16 f2bf(float f) {
    union { float f; u32 i; } v; v.f = f;
    u32 i = v.i + 0x7fffu + ((v.i >> 16) & 1u);
    return (u16)(i >> 16);
}
__device__ inline float seluf(float x) {
    const float sc = 1.0507009873554805f, al = 1.6732632423543772f;
    return x > 0.f ? sc * x : sc * al * expm1f(x);
}
__device__ inline short8 packbf8(float4 f0, float4 f1) {
    short8 a;
    a[0] = (short)f2bf(f0.x); a[1] = (short)f2bf(f0.y);
    a[2] = (short)f2bf(f0.z); a[3] = (short)f2bf(f0.w);
    a[4] = (short)f2bf(f1.x); a[5] = (short)f2bf(f1.y);
    a[6] = (short)f2bf(f1.z); a[7] = (short)f2bf(f1.w);
    return a;
}

// ---------------- dtype sniffer ----------------
__global__ void detectk(const void* __restrict__ demb, u32* __restrict__ flag) {
    const u16* p = (const u16*)demb;
    int tid = threadIdx.x;  // 256
    int sane = 0;
    #pragma unroll
    for (int i = 0; i < 2; i++) {
        u16 u = p[4 * tid + 2 * i];
        int e = (u >> 7) & 0xFF;
        if (u == 0 || (e >= 0x66 && e <= 0x8C)) sane++;
    }
    __shared__ int red[256];
    red[tid] = sane; __syncthreads();
    for (int o = 128; o > 0; o >>= 1) {
        if (tid < o) red[tid] += red[tid + o];
        __syncthreads();
    }
    if (tid == 0) flag[0] = (red[0] < 300) ? 1u : 0u;
}

// ---------------- canonical bf16 conversion (26 segments, one launch) -------
#define NSEG 26
struct CvtArgs { const void* src[NSEG]; int off[NSEG]; int n[NSEG]; };

__global__ __launch_bounds__(256) void cvtk(CvtArgs a, u16* __restrict__ base,
                                            const u32* __restrict__ flag) {
    int seg = blockIdx.y;
    int n = a.n[seg];
    const void* s = a.src[seg];
    u16* d = base + a.off[seg];
    bool f32 = flag[0] != 0;
    int stride = gridDim.x * blockDim.x;
    for (int i = blockIdx.x * blockDim.x + threadIdx.x; i < n; i += stride)
        d[i] = f32 ? f2bf(((const float*)s)[i]) : ((const u16*)s)[i];
}

// ---------------- transpose (bf16, tiled 32x32) ----------------
__device__ inline void tpose_body(const u16* in, int R, int C,
                                  u16* out, int ldo, int ooff,
                                  u16 (*tile)[33]) {
    int c0 = blockIdx.x * 32, r0 = blockIdx.y * 32;
    int x = c0 + threadIdx.x;
    for (int i = threadIdx.y; i < 32; i += 8) {
        int r = r0 + i;
        tile[i][threadIdx.x] = (r < R && x < C) ? in[(size_t)r * C + x] : (u16)0;
    }
    __syncthreads();
    int rr = r0 + threadIdx.x;
    for (int i = threadIdx.y; i < 32; i += 8) {
        int cc = c0 + i;
        if (cc < C && rr < R) out[(size_t)cc * ldo + ooff + rr] = tile[threadIdx.x][i];
    }
}

__global__ void tpose_embs(const u16* __restrict__ demb, const u16* __restrict__ pemb,
                           u16* __restrict__ disT, u16* __restrict__ drugT) {
    __shared__ u16 tile[32][33];
    if (blockIdx.z == 0) tpose_body(demb, ND, 128, disT, ND, 0, tile);
    else                 tpose_body(pemb, ND, 128, drugT, ND, 0, tile);
}

__global__ void tpose_smalls(const u16* s0, const u16* s1, const u16* s2,
                             const u16* s3, const u16* s4, const u16* s5,
                             u16* W1T, u16* W2T, u16* WcTe, u16* WcTp) {
    __shared__ u16 tile[32][33];
    const u16* in; u16* out; int ldo, ooff;
    switch (blockIdx.z) {
        case 0:  in = s0; out = W1T;  ldo = 128; ooff = 0;   break;
        case 1:  in = s1; out = W2T;  ldo = 128; ooff = 0;   break;
        case 2:  in = s2; out = WcTe; ldo = 256; ooff = 0;   break;
        case 3:  in = s3; out = WcTe; ldo = 256; ooff = 128; break;
        case 4:  in = s4; out = WcTp; ldo = 256; ooff = 0;   break;
        default: in = s5; out = WcTp; ldo = 256; ooff = 128; break;
    }
    tpose_body(in, 128, 128, out, ldo, ooff, tile);
}

// ---------------- combined biases ----------------
__global__ void biasc(const u16* a0, const u16* a1, const u16* a2, u16* o0,
                      const u16* b0, const u16* b1, const u16* b2, u16* o1) {
    int t = threadIdx.x;  // 128
    o0[t] = f2bf(bf2f(a0[t]) + bf2f(a1[t]) + bf2f(a2[t]));
    o1[t] = f2bf(bf2f(b0[t]) + bf2f(b1[t]) + bf2f(b2[t]));
}

// ---------------- inverse degree ----------------
__global__ __launch_bounds__(256) void degk(
    const void* __restrict__ e_e, float* __restrict__ dinv_e,
    const void* __restrict__ p_p, float* __restrict__ dinv_p,
    const u32* __restrict__ flag) {
    int row = blockIdx.x, tid = threadIdx.x;
    const void* ab = blockIdx.y ? p_p : e_e;
    float* o = blockIdx.y ? dinv_p : dinv_e;
    bool f32 = flag[0] != 0;
    float s = 0.f;
    if (f32) {
        const float4* a4 = (const float4*)((const float*)ab + (size_t)row * 2048) + tid * 2;
        float4 v0 = a4[0], v1 = a4[1];
        s = v0.x + v0.y + v0.z + v0.w + v1.x + v1.y + v1.z + v1.w;
    } else {
        const uint4* a4 = (const uint4*)((const u16*)ab + (size_t)row * 2048) + tid;
        uint4 v = a4[0];
        u32 u[4] = {v.x, v.y, v.z, v.w};
        #pragma unroll
        for (int c = 0; c < 4; c++)
            s += bf2f((u16)(u[c] & 0xffff)) + bf2f((u16)(u[c] >> 16));
    }
    __shared__ float red[256];
    red[tid] = s; __syncthreads();
    for (int ofs = 128; ofs > 0; ofs >>= 1) {
        if (tid < ofs) red[tid] += red[tid + ofs];
        __syncthreads();
    }
    if (tid == 0) o[row] = 1.f / (red[0] + 1e-8f);
}

// ---------------- ko / qs projections ----------
__global__ __launch_bounds__(128) void koqs(
    const u16* __restrict__ demb, const u16* __restrict__ pemb,
    const u16* __restrict__ Wa1d, const u16* __restrict__ ba1d,
    const u16* __restrict__ Wa1p, const u16* __restrict__ ba1p,
    float* __restrict__ ko_d, float* __restrict__ qs_d,
    float* __restrict__ ko_p, float* __restrict__ qs_p) {
    int row = blockIdx.x, m = blockIdx.y, tid = threadIdx.x;
    const u16* src; const u16* W; const u16* bias; float* out;
    switch (m) {
        case 0:  src = pemb; W = Wa1d;            bias = nullptr; out = ko_d; break;
        case 1:  src = demb; W = Wa1d + 128 * 32; bias = ba1d;    out = qs_d; break;
        case 2:  src = demb; W = Wa1p;            bias = nullptr; out = ko_p; break;
        default: src = pemb; W = Wa1p + 128 * 32; bias = ba1p;    out = qs_p; break;
    }
    __shared__ float x[128];
    __shared__ float red[128];
    x[tid] = bf2f(src[(size_t)row * 128 + tid]);
    __syncthreads();
    int a = tid & 31, part = tid >> 5;
    float s = 0.f;
    #pragma unroll
    for (int k = 0; k < 32; k++) s += x[part * 32 + k] * bf2f(W[(part * 32 + k) * 32 + a]);
    red[tid] = s;
    __syncthreads();
    if (part == 0) {
        float t = red[a] + red[a + 32] + red[a + 64] + red[a + 96];
        if (bias) t += bf2f(bias[a]);
        out[(size_t)row * 32 + a] = t;
    }
}

// ---------------- attention v4: wave-per-row, register q/w2, j-split --------
// grid (512, 4): x = 4-row group, y = 512-col j-split. block 256 (4 waves).
// Writes exp weights (bf16) + partial row sums sums[y][row] (no atomics).
__global__ __launch_bounds__(256) void attnw4(
    const float* __restrict__ qs, const float* __restrict__ ko,
    const void* __restrict__ adjv, int transposed,
    const u16* __restrict__ w2, const u16* __restrict__ b2p,
    u16* __restrict__ outw, float* __restrict__ sums,
    const u32* __restrict__ flag) {
    __shared__ float tile[512][5];
    int tid = threadIdx.x;
    int lane = tid & 63, wv = tid >> 6;
    int r0 = blockIdx.x * 4;
    int row = r0 + wv;
    int jbase = blockIdx.y * 512;
    bool f32a = flag[0] != 0;
    if (transposed) {
        #pragma unroll
        for (int it = 0; it < 2; it++) {
            int jt = it * 256 + tid;
            if (f32a) {
                const float4* p = (const float4*)((const float*)adjv +
                                  (size_t)(jbase + jt) * 2048 + r0);
                float4 v = p[0];
                tile[jt][0] = v.x; tile[jt][1] = v.y;
                tile[jt][2] = v.z; tile[jt][3] = v.w;
            } else {
                const u32* p = (const u32*)((const u16*)adjv +
                               (size_t)(jbase + jt) * 2048 + r0);
                u32 a0 = p[0], a1 = p[1];
                tile[jt][0] = bf2f((u16)(a0 & 0xffff)); tile[jt][1] = bf2f((u16)(a0 >> 16));
                tile[jt][2] = bf2f((u16)(a1 & 0xffff)); tile[jt][3] = bf2f((u16)(a1 >> 16));
            }
        }
        __syncthreads();
    }
    int urow = __builtin_amdgcn_readfirstlane(row);
    const float* qrow = qs + (size_t)urow * 32;
    float q[32], w2v[32];
    #pragma unroll
    for (int a = 0; a < 32; a++) q[a] = qrow[a];
    #pragma unroll
    for (int a = 0; a < 32; a++) w2v[a] = bf2f(w2[a]);
    float b2 = bf2f(b2p[0]);
    float ls = 0.f;
    #pragma unroll 2
    for (int jj = 0; jj < 8; jj++) {
        int j = jbase + jj * 64 + lane;
        const float4* kp = (const float4*)(ko + (size_t)j * 32);
        float s = 0.f;
        #pragma unroll
        for (int qd = 0; qd < 8; qd++) {
            float4 kv = kp[qd];
            s += fmaxf(q[qd * 4 + 0] + kv.x, 0.f) * w2v[qd * 4 + 0];
            s += fmaxf(q[qd * 4 + 1] + kv.y, 0.f) * w2v[qd * 4 + 1];
            s += fmaxf(q[qd * 4 + 2] + kv.z, 0.f) * w2v[qd * 4 + 2];
            s += fmaxf(q[qd * 4 + 3] + kv.w, 0.f) * w2v[qd * 4 + 3];
        }
        s = fmaxf(s + b2, 0.f);
        float av;
        if (transposed) av = tile[jj * 64 + lane][wv];
        else av = f32a ? ((const float*)adjv)[(size_t)row * 2048 + j]
                       : bf2f(((const u16*)adjv)[(size_t)row * 2048 + j]);
        float e = __expf(s * av);
        outw[(size_t)row * 2048 + j] = f2bf(e);
        ls += e;
    }
    #pragma unroll
    for (int o = 32; o > 0; o >>= 1) ls += __shfl_down(ls, o, 64);
    if (lane == 0) sums[(size_t)blockIdx.y * 2048 + row] = ls;
}

// ---------------- MFMA GEMM, 4-deep pipeline, z-batched -------------------
// rsmode: 0 none, 1 multiply rs[row], 2 multiply 1/(rs[row]+rs[row+2048]+rs[row+4096]+rs[row+6144])
struct GD {
    const void* A[2]; const u16* BT[2]; u16* C[2];
    const u16* bias[2]; const float* rs[2];
    int lda[2], ldb[2], ldc[2], coff[2], ksteps[2], act[2], araw[2], rsmode[2];
};

__global__ __launch_bounds__(256) void gemm16b(GD g, const u32* __restrict__ flag) {
    int z = blockIdx.y;
    bool af32 = g.araw[z] && (flag[0] != 0);
    const u16*   A16 = (const u16*)g.A[z];
    const float* A32 = (const float*)g.A[z];
    int lda = g.lda[z], ldb = g.ldb[z];
    int tid = threadIdx.x;
    int lane = tid & 63, wv = tid >> 6;
    int mrow = lane & 15, quad = lane >> 4;
    int m0 = blockIdx.x * 16;
    int c0 = wv * 32;
    size_t aoff = (size_t)(m0 + mrow) * lda + quad * 8;
    const u16* b0p = g.BT[z] + (size_t)(c0 + mrow) * ldb + quad * 8;
    const u16* b1p = g.BT[z] + (size_t)(c0 + 16 + mrow) * ldb + quad * 8;
    f32x4 acc0 = {0.f, 0.f, 0.f, 0.f}, acc1 = {0.f, 0.f, 0.f, 0.f};
    int ks = g.ksteps[z];   // always a multiple of 4 here (64, 8, 4)

    auto aload = [&](int k) -> short8 {
        if (af32) {
            const float4* p = (const float4*)(A32 + aoff + (size_t)k * 32);
            return packbf8(p[0], p[1]);
        }
        return *(const short8*)(A16 + aoff + (size_t)k * 32);
    };
    short8 ab[4], b0b[4], b1b[4];
    #pragma unroll
    for (int i = 0; i < 4; i++) {
        if (i < ks) {
            ab[i]  = aload(i);
            b0b[i] = *(const short8*)(b0p + (size_t)i * 32);
            b1b[i] = *(const short8*)(b1p + (size_t)i * 32);
        }
    }
    for (int k = 0; k < ks; k += 4) {
        #pragma unroll
        for (int u = 0; u < 4; u++) {
            int kc = k + u;
            acc0 = __builtin_amdgcn_mfma_f32_16x16x32_bf16(ab[u], b0b[u], acc0, 0, 0, 0);
            acc1 = __builtin_amdgcn_mfma_f32_16x16x32_bf16(ab[u], b1b[u], acc1, 0, 0, 0);
            int kn = kc + 4;
            if (kn < ks) {
                ab[u]  = aload(kn);
                b0b[u] = *(const short8*)(b0p + (size_t)kn * 32);
                b1b[u] = *(const short8*)(b1p + (size_t)kn * 32);
            }
        }
    }

    const float* rs = g.rs[z];
    int rsmode = g.rsmode[z];
    const u16* bi = g.bias[z];
    u16* C = g.C[z];
    int ldc = g.ldc[z], coff = g.coff[z], act = g.act[z];
    int n0 = c0 + mrow, n1 = n0 + 16;
    float bv0 = bi ? bf2f(bi[n0]) : 0.f;
    float bv1 = bi ? bf2f(bi[n1]) : 0.f;
    #pragma unroll
    for (int r = 0; r < 4; r++) {
        int row = m0 + quad * 4 + r;
        float v0 = acc0[r], v1 = acc1[r];
        if (rsmode == 1) { float sc = rs[row]; v0 *= sc; v1 *= sc; }
        else if (rsmode == 2) {
            float sc = 1.f / (rs[row] + rs[row + 2048] + rs[row + 4096] + rs[row + 6144]);
            v0 *= sc; v1 *= sc;
        }
        v0 += bv0; v1 += bv1;
        if (act) { v0 = seluf(v0); v1 = seluf(v1); }
        C[(size_t)row * ldc + coff + n0] = f2bf(v0);
        C[(size_t)row * ldc + coff + n1] = f2bf(v1);
    }
}

// ---------------- pair gather ----------
__global__ __launch_bounds__(256) void xbuild(
    const u16* __restrict__ he, const u16* __restrict__ hp,
    const int* __restrict__ di, const int* __restrict__ dr, u16* __restrict__ X) {
    int idx = blockIdx.x * 256 + threadIdx.x;  // < B*64
    int d2 = idx & 63;
    int b = idx >> 6;
    int ia = di[b], ic = dr[b];
    u32 ue = ((const u32*)he)[ia * 64 + d2];
    u32 up = ((const u32*)hp)[ic * 64 + d2];
    float lo = bf2f((u16)(ue & 0xffff)) * bf2f((u16)(up & 0xffff));
    float hi = bf2f((u16)(ue >> 16)) * bf2f((u16)(up >> 16));
    ((u32*)X)[idx] = (u32)f2bf(lo) | ((u32)f2bf(hi) << 16);
}

// ---------------- z, sigmoid, loss (FLOAT32 out: out[0]=loss, out[1+b]=sig) --
__global__ __launch_bounds__(256) void zloss(
    const u16* __restrict__ X2, const u16* __restrict__ wpred,
    const u16* __restrict__ bpred, const int* __restrict__ labels,
    float* __restrict__ out, float* __restrict__ part) {
    __shared__ float wp[128];
    __shared__ float ls[256];
    int tid = threadIdx.x;
    if (tid < 128) wp[tid] = bf2f(wpred[tid]);
    __syncthreads();
    int b = blockIdx.x * 256 + tid;
    const uint4* xp = (const uint4*)(X2 + (size_t)b * 128);
    float z = 0.f;
    #pragma unroll
    for (int i = 0; i < 16; i++) {
        uint4 q = xp[i];
        u32 u[4] = {q.x, q.y, q.z, q.w};
        #pragma unroll
        for (int c = 0; c < 4; c++) {
            z += bf2f((u16)(u[c] & 0xffff)) * wp[i * 8 + c * 2];
            z += bf2f((u16)(u[c] >> 16)) * wp[i * 8 + c * 2 + 1];
        }
    }
    z += bf2f(bpred[0]);
    out[1 + b] = 1.f / (1.f + __expf(-z));
    float y = (float)labels[b];
    ls[tid] = fmaxf(z, 0.f) - z * y + log1pf(__expf(-fabsf(z)));
    __syncthreads();
    for (int o = 128; o > 0; o >>= 1) {
        if (tid < o) ls[tid] += ls[tid + o];
        __syncthreads();
    }
    if (tid == 0) part[blockIdx.x] = ls[0];
}

__global__ void finloss(const float* __restrict__ part, float* __restrict__ out) {
    __shared__ float s[64];
    s[threadIdx.x] = part[threadIdx.x];
    __syncthreads();
    for (int o = 32; o > 0; o >>= 1) {
        if (threadIdx.x < o) s[threadIdx.x] += s[threadIdx.x + o];
        __syncthreads();
    }
    if (threadIdx.x == 0) out[0] = s[0] * (1.f / 16384.f);
}

// ---------------- launch ----------------
extern "C" void kernel_launch(void* const* d_in, const int* in_sizes, int n_in,
                              void* d_out, int out_size, void* d_ws, size_t ws_size,
                              hipStream_t stream) {
    const void* e_p_adj = d_in[0];
    const void* e_e_adj = d_in[1];
    const void* p_p_adj = d_in[2];
    const int* in_dis  = (const int*)d_in[3];
    const int* in_drug = (const int*)d_in[4];
    const int* labels  = (const int*)d_in[5];
    float* out = (float*)d_out;

    // -------- workspace layout (~15.5 MB) --------
    char* ws = (char*)d_ws;
    size_t off = 0;
    auto take = [&](size_t bytes) { char* p = ws + off; off = (off + bytes + 255) & ~(size_t)255; return p; };
    u16*   Wbuf  = (u16*)take((size_t)2048 * 2048 * 2);   // exp weights; later X+X1
    u16*   drugT = (u16*)take((size_t)128 * 2048 * 2);    // --- X2 overlays drugT..A_p ---
    u16*   disT  = (u16*)take((size_t)128 * 2048 * 2);
    float* ko_d  = (float*)take((size_t)2048 * 32 * 4);
    float* qs_d  = (float*)take((size_t)2048 * 32 * 4);
    float* ko_p  = (float*)take((size_t)2048 * 32 * 4);
    float* qs_p  = (float*)take((size_t)2048 * 32 * 4);
    u16*   A_e   = (u16*)take((size_t)2048 * 256 * 2);
    u16*   A_p   = (u16*)take((size_t)2048 * 256 * 2);
    u16*   WcTe  = (u16*)take((size_t)128 * 256 * 2);
    u16*   WcTp  = (u16*)take((size_t)128 * 256 * 2);
    u16*   W1T   = (u16*)take((size_t)128 * 128 * 2);
    u16*   W2T   = (u16*)take((size_t)128 * 128 * 2);
    u16*   b_e   = (u16*)take(256);
    u16*   b_p   = (u16*)take(256);
    u16*   h_e   = (u16*)take((size_t)2048 * 128 * 2);
    u16*   h_p   = (u16*)take((size_t)2048 * 128 * 2);
    float* dinv_e = (float*)take(2048 * 4);
    float* dinv_p = (float*)take(2048 * 4);
    float* sumsD  = (float*)take(4 * 2048 * 4);
    float* sumsP  = (float*)take(4 * 2048 * 4);
    float* part  = (float*)take(64 * 4);
    u16*   canon = (u16*)take((size_t)700000 * 2);
    u32*   flag  = (u32*)take(256);
    u16* X  = Wbuf;
    u16* X1 = Wbuf + (size_t)BB * 128;
    u16* X2 = drugT;   // 4 MB over drugT..A_p

    // -------- canonical parameter table --------
    const int segidx[NSEG] = {6, 7, 14, 18, 8, 22, 11, 24, 26, 28,
                              15, 16, 17, 19, 20, 21,
                              9, 10, 12, 13, 23, 25, 27, 29, 30, 31};
    const int segn[NSEG]   = {262144, 262144, 8192, 8192, 16384, 16384, 16384, 16384, 16384, 16384,
                              32, 32, 1, 32, 32, 1,
                              128, 128, 128, 128, 128, 128, 128, 128, 128, 1};
    CvtArgs ca;
    u16* cp[NSEG];
    {
        int o = 0;
        for (int i = 0; i < NSEG; i++) {
            ca.src[i] = d_in[segidx[i]];
            ca.off[i] = o;
            ca.n[i] = segn[i];
            cp[i] = canon + o;
            o += (segn[i] + 15) & ~15;
        }
    }
    u16 *cdemb = cp[0], *cpemb = cp[1], *cWa1d = cp[2], *cWa1p = cp[3];
    u16 *cWdg = cp[4], *cWd2 = cp[5], *cWpg = cp[6], *cWp3 = cp[7];
    u16 *cW1 = cp[8], *cW2 = cp[9];
    u16 *cba1d = cp[10], *cWa2d = cp[11], *cba2d = cp[12];
    u16 *cba1p = cp[13], *cWa2p = cp[14], *cba2p = cp[15];
    u16 *cbdg_lin = cp[16], *cbdg = cp[17], *cbpg_lin = cp[18], *cbpg = cp[19];
    u16 *cbd2 = cp[20], *cbp3 = cp[21], *cmb1 = cp[22], *cmb2 = cp[23];
    u16 *cWpred = cp[24], *cbpred = cp[25];

    // -------- 0. dtype detection + canonicalization --------
    detectk<<<1, 256, 0, stream>>>(d_in[6], flag);
    cvtk<<<dim3(64, NSEG), 256, 0, stream>>>(ca, canon, flag);

    // -------- 1. prep --------
    tpose_embs<<<dim3(4, 64, 2), dim3(32, 8), 0, stream>>>(cdemb, cpemb, disT, drugT);
    tpose_smalls<<<dim3(4, 4, 6), dim3(32, 8), 0, stream>>>(
        cW1, cW2, cWdg, cWd2, cWpg, cWp3, W1T, W2T, WcTe, WcTp);
    biasc<<<1, 128, 0, stream>>>(cbdg_lin, cbdg, cbd2, b_e, cbpg_lin, cbpg, cbp3, b_p);
    degk<<<dim3(2048, 2), 256, 0, stream>>>(e_e_adj, dinv_e, p_p_adj, dinv_p, flag);
    koqs<<<dim3(2048, 4), 128, 0, stream>>>(cdemb, cpemb, cWa1d, cba1d, cWa1p, cba1p,
                                            ko_d, qs_d, ko_p, qs_p);

    auto mkgd = [](const void* A0, int lda0, const u16* BT0, int ldb0, u16* C0,
                   int ldc0, int coff0, int ks0, const u16* bi0, const float* rs0,
                   int act0, int araw0, int rm0,
                   const void* A1, int lda1, const u16* BT1, int ldb1, u16* C1,
                   int ldc1, int coff1, int ks1, const u16* bi1, const float* rs1,
                   int act1, int araw1, int rm1) {
        GD g;
        g.A[0] = A0; g.lda[0] = lda0; g.BT[0] = BT0; g.ldb[0] = ldb0;
        g.C[0] = C0; g.ldc[0] = ldc0; g.coff[0] = coff0; g.ksteps[0] = ks0;
        g.bias[0] = bi0; g.rs[0] = rs0; g.act[0] = act0; g.araw[0] = araw0; g.rsmode[0] = rm0;
        g.A[1] = A1; g.lda[1] = lda1; g.BT[1] = BT1; g.ldb[1] = ldb1;
        g.C[1] = C1; g.ldc[1] = ldc1; g.coff[1] = coff1; g.ksteps[1] = ks1;
        g.bias[1] = bi1; g.rs[1] = rs1; g.act[1] = act1; g.araw[1] = araw1; g.rsmode[1] = rm1;
        return g;
    };

    // -------- 2. disease-side attention, then {att-agg, knn-agg} batch ------
    attnw4<<<dim3(512, 4), 256, 0, stream>>>(qs_d, ko_d, e_p_adj, 0, cWa2d, cba2d,
                                             Wbuf, sumsD, flag);
    {
        GD g = mkgd(Wbuf, 2048, drugT, 2048, A_e, 256, 0, 64, nullptr, sumsD, 0, 0, 2,
                    e_e_adj, 2048, disT, 2048, A_e, 256, 128, 64, nullptr, dinv_e, 0, 1, 1);
        gemm16b<<<dim3(128, 2), 256, 0, stream>>>(g, flag);
    }

    // -------- 3. drug-side attention (transposed adj), then batch ----------
    attnw4<<<dim3(512, 4), 256, 0, stream>>>(qs_p, ko_p, e_p_adj, 1, cWa2p, cba2p,
                                             Wbuf, sumsP, flag);
    {
        GD g = mkgd(Wbuf, 2048, disT, 2048, A_p, 256, 0, 64, nullptr, sumsP, 0, 0, 2,
                    p_p_adj, 2048, drugT, 2048, A_p, 256, 128, 64, nullptr, dinv_p, 0, 1, 1);
        gemm16b<<<dim3(128, 2), 256, 0, stream>>>(g, flag);
    }

    // -------- 4. combine GEMMs (bias + SELU), batched ----------------------
    {
        GD g = mkgd(A_e, 256, WcTe, 256, h_e, 128, 0, 8, b_e, nullptr, 1, 0, 0,
                    A_p, 256, WcTp, 256, h_p, 128, 0, 8, b_p, nullptr, 1, 0, 0);
        gemm16b<<<dim3(128, 2), 256, 0, stream>>>(g, flag);
    }

    // -------- 5. pair MLP --------
    xbuild<<<4096, 256, 0, stream>>>(h_e, h_p, in_dis, in_drug, X);
    {
        GD g = mkgd(X, 128, W1T, 128, X1, 128, 0, 4, cmb1, nullptr, 1, 0, 0,
                    X, 128, W1T, 128, X1, 128, 0, 4, cmb1, nullptr, 1, 0, 0);
        gemm16b<<<dim3(1024, 1), 256, 0, stream>>>(g, flag);
    }
    {
        GD g = mkgd(X1, 128, W2T, 128, X2, 128, 0, 4, cmb2, nullptr, 1, 0, 0,
                    X1, 128, W2T, 128, X2, 128, 0, 4, cmb2, nullptr, 1, 0, 0);
        gemm16b<<<dim3(1024, 1), 256, 0, stream>>>(g, flag);
    }

    // -------- 6. z / sigmoid / loss --------
    zloss<<<64, 256, 0, stream>>>(X2, cWpred, cbpred, labels, out, part);
    finloss<<<1, 64, 0, stream>>>(part, out);
}

// Round 9
// 386.779 us; speedup vs baseline: 1.1569x; 1.0523x over previous
//
#include <hip/hip_runtime.h>

#define ND   2048
#define BB   16384

typedef unsigned short u16;
typedef unsigned int u32;
typedef __attribute__((ext_vector_type(8))) short short8;
typedef __attribute__((ext_vector_type(4))) float f32x4;

__device__ inline float bf2f(u16 u) {
    union { u32 i; float f; } v; v.i = ((u32)u) << 16; return v.f;
}
__device__ inline u16 f2bf(float f) {
    union { float f; u32 i; } v; v.f = f;
    u32 i = v.i + 0x7fffu + ((v.i >> 16) & 1u);
    return (u16)(i >> 16);
}
__device__ inline float seluf(float x) {
    const float sc = 1.0507009873554805f, al = 1.6732632423543772f;
    return x > 0.f ? sc * x : sc * al * expm1f(x);
}
__device__ inline short8 packbf8(float4 f0, float4 f1) {
    short8 a;
    a[0] = (short)f2bf(f0.x); a[1] = (short)f2bf(f0.y);
    a[2] = (short)f2bf(f0.z); a[3] = (short)f2bf(f0.w);
    a[4] = (short)f2bf(f1.x); a[5] = (short)f2bf(f1.y);
    a[6] = (short)f2bf(f1.z); a[7] = (short)f2bf(f1.w);
    return a;
}

// ---------------- dtype sniffer ----------------
__global__ void detectk(const void* __restrict__ demb, u32* __restrict__ flag) {
    const u16* p = (const u16*)demb;
    int tid = threadIdx.x;  // 256
    int sane = 0;
    #pragma unroll
    for (int i = 0; i < 2; i++) {
        u16 u = p[4 * tid + 2 * i];
        int e = (u >> 7) & 0xFF;
        if (u == 0 || (e >= 0x66 && e <= 0x8C)) sane++;
    }
    __shared__ int red[256];
    red[tid] = sane; __syncthreads();
    for (int o = 128; o > 0; o >>= 1) {
        if (tid < o) red[tid] += red[tid + o];
        __syncthreads();
    }
    if (tid == 0) flag[0] = (red[0] < 300) ? 1u : 0u;
}

// ---------------- canonical bf16 conversion (26 segments, one launch) -------
#define NSEG 26
struct CvtArgs { const void* src[NSEG]; int off[NSEG]; int n[NSEG]; };

__global__ __launch_bounds__(256) void cvtk(CvtArgs a, u16* __restrict__ base,
                                            const u32* __restrict__ flag) {
    int seg = blockIdx.y;
    int n = a.n[seg];
    const void* s = a.src[seg];
    u16* d = base + a.off[seg];
    bool f32 = flag[0] != 0;
    int stride = gridDim.x * blockDim.x;
    for (int i = blockIdx.x * blockDim.x + threadIdx.x; i < n; i += stride)
        d[i] = f32 ? f2bf(((const float*)s)[i]) : ((const u16*)s)[i];
}

// ---------------- transpose (bf16, tiled 32x32) ----------------
__device__ inline void tpose_body(const u16* in, int R, int C,
                                  u16* out, int ldo, int ooff,
                                  u16 (*tile)[33]) {
    int c0 = blockIdx.x * 32, r0 = blockIdx.y * 32;
    int x = c0 + threadIdx.x;
    for (int i = threadIdx.y; i < 32; i += 8) {
        int r = r0 + i;
        tile[i][threadIdx.x] = (r < R && x < C) ? in[(size_t)r * C + x] : (u16)0;
    }
    __syncthreads();
    int rr = r0 + threadIdx.x;
    for (int i = threadIdx.y; i < 32; i += 8) {
        int cc = c0 + i;
        if (cc < C && rr < R) out[(size_t)cc * ldo + ooff + rr] = tile[threadIdx.x][i];
    }
}

__global__ void tpose_embs(const u16* __restrict__ demb, const u16* __restrict__ pemb,
                           u16* __restrict__ disT, u16* __restrict__ drugT) {
    __shared__ u16 tile[32][33];
    if (blockIdx.z == 0) tpose_body(demb, ND, 128, disT, ND, 0, tile);
    else                 tpose_body(pemb, ND, 128, drugT, ND, 0, tile);
}

__global__ void tpose_smalls(const u16* s0, const u16* s1, const u16* s2,
                             const u16* s3, const u16* s4, const u16* s5,
                             u16* W1T, u16* W2T, u16* WcTe, u16* WcTp) {
    __shared__ u16 tile[32][33];
    const u16* in; u16* out; int ldo, ooff;
    switch (blockIdx.z) {
        case 0:  in = s0; out = W1T;  ldo = 128; ooff = 0;   break;
        case 1:  in = s1; out = W2T;  ldo = 128; ooff = 0;   break;
        case 2:  in = s2; out = WcTe; ldo = 256; ooff = 0;   break;
        case 3:  in = s3; out = WcTe; ldo = 256; ooff = 128; break;
        case 4:  in = s4; out = WcTp; ldo = 256; ooff = 0;   break;
        default: in = s5; out = WcTp; ldo = 256; ooff = 128; break;
    }
    tpose_body(in, 128, 128, out, ldo, ooff, tile);
}

// ---------------- combined biases ----------------
__global__ void biasc(const u16* a0, const u16* a1, const u16* a2, u16* o0,
                      const u16* b0, const u16* b1, const u16* b2, u16* o1) {
    int t = threadIdx.x;  // 128
    o0[t] = f2bf(bf2f(a0[t]) + bf2f(a1[t]) + bf2f(a2[t]));
    o1[t] = f2bf(bf2f(b0[t]) + bf2f(b1[t]) + bf2f(b2[t]));
}

// ---------------- inverse degree ----------------
__global__ __launch_bounds__(256) void degk(
    const void* __restrict__ e_e, float* __restrict__ dinv_e,
    const void* __restrict__ p_p, float* __restrict__ dinv_p,
    const u32* __restrict__ flag) {
    int row = blockIdx.x, tid = threadIdx.x;
    const void* ab = blockIdx.y ? p_p : e_e;
    float* o = blockIdx.y ? dinv_p : dinv_e;
    bool f32 = flag[0] != 0;
    float s = 0.f;
    if (f32) {
        const float4* a4 = (const float4*)((const float*)ab + (size_t)row * 2048) + tid * 2;
        float4 v0 = a4[0], v1 = a4[1];
        s = v0.x + v0.y + v0.z + v0.w + v1.x + v1.y + v1.z + v1.w;
    } else {
        const uint4* a4 = (const uint4*)((const u16*)ab + (size_t)row * 2048) + tid;
        uint4 v = a4[0];
        u32 u[4] = {v.x, v.y, v.z, v.w};
        #pragma unroll
        for (int c = 0; c < 4; c++)
            s += bf2f((u16)(u[c] & 0xffff)) + bf2f((u16)(u[c] >> 16));
    }
    __shared__ float red[256];
    red[tid] = s; __syncthreads();
    for (int ofs = 128; ofs > 0; ofs >>= 1) {
        if (tid < ofs) red[tid] += red[tid + ofs];
        __syncthreads();
    }
    if (tid == 0) o[row] = 1.f / (red[0] + 1e-8f);
}

// ---------------- ko / qs projections ----------
__global__ __launch_bounds__(128) void koqs(
    const u16* __restrict__ demb, const u16* __restrict__ pemb,
    const u16* __restrict__ Wa1d, const u16* __restrict__ ba1d,
    const u16* __restrict__ Wa1p, const u16* __restrict__ ba1p,
    float* __restrict__ ko_d, float* __restrict__ qs_d,
    float* __restrict__ ko_p, float* __restrict__ qs_p) {
    int row = blockIdx.x, m = blockIdx.y, tid = threadIdx.x;
    const u16* src; const u16* W; const u16* bias; float* out;
    switch (m) {
        case 0:  src = pemb; W = Wa1d;            bias = nullptr; out = ko_d; break;
        case 1:  src = demb; W = Wa1d + 128 * 32; bias = ba1d;    out = qs_d; break;
        case 2:  src = demb; W = Wa1p;            bias = nullptr; out = ko_p; break;
        default: src = pemb; W = Wa1p + 128 * 32; bias = ba1p;    out = qs_p; break;
    }
    __shared__ float x[128];
    __shared__ float red[128];
    x[tid] = bf2f(src[(size_t)row * 128 + tid]);
    __syncthreads();
    int a = tid & 31, part = tid >> 5;
    float s = 0.f;
    #pragma unroll
    for (int k = 0; k < 32; k++) s += x[part * 32 + k] * bf2f(W[(part * 32 + k) * 32 + a]);
    red[tid] = s;
    __syncthreads();
    if (part == 0) {
        float t = red[a] + red[a + 32] + red[a + 64] + red[a + 96];
        if (bias) t += bf2f(bias[a]);
        out[(size_t)row * 32 + a] = t;
    }
}

// ---------------- attention v5: 16 rows/block, wave-per-row, line-complete --
// grid (128, 8, nz). block 1024 (16 waves). Transposed staging reads FULL
// 64B lines (16 f32 of 16 consecutive output-rows per j).
struct AW {
    const float* qs[2]; const float* ko[2];
    const u16* w2[2]; const u16* b2[2];
    u16* outw[2]; float* sums[2];
    int transposed[2];
};

__global__ __launch_bounds__(1024) void attnw5(AW a, const void* __restrict__ adj,
                                               const u32* __restrict__ flag) {
    __shared__ float tile[256][17];
    int z = blockIdx.z;
    int tid = threadIdx.x;
    int lane = tid & 63, wv = tid >> 6;      // wv 0..15 = row within block
    int r0 = blockIdx.x * 16;
    int row = r0 + wv;
    int jbase = blockIdx.y * 256;
    bool f32a = flag[0] != 0;
    if (a.transposed[z]) {
        int j = tid >> 2, part = tid & 3;    // j 0..255, part 0..3 (4 elems each)
        if (f32a) {
            const float4* p = (const float4*)((const float*)adj +
                              (size_t)(jbase + j) * 2048 + r0 + part * 4);
            float4 v = *p;
            tile[j][part * 4 + 0] = v.x; tile[j][part * 4 + 1] = v.y;
            tile[j][part * 4 + 2] = v.z; tile[j][part * 4 + 3] = v.w;
        } else {
            const u32* p = (const u32*)((const u16*)adj +
                           (size_t)(jbase + j) * 2048 + r0 + part * 4);
            u32 a0 = p[0], a1 = p[1];
            tile[j][part * 4 + 0] = bf2f((u16)(a0 & 0xffff));
            tile[j][part * 4 + 1] = bf2f((u16)(a0 >> 16));
            tile[j][part * 4 + 2] = bf2f((u16)(a1 & 0xffff));
            tile[j][part * 4 + 3] = bf2f((u16)(a1 >> 16));
        }
        __syncthreads();
    }
    int urow = __builtin_amdgcn_readfirstlane(row);
    const float* qrow = a.qs[z] + (size_t)urow * 32;
    const float* ko = a.ko[z];
    float q[32], w2v[32];
    #pragma unroll
    for (int i = 0; i < 32; i++) q[i] = qrow[i];
    #pragma unroll
    for (int i = 0; i < 32; i++) w2v[i] = bf2f(a.w2[z][i]);
    float b2 = bf2f(a.b2[z][0]);
    u16* outw = a.outw[z];
    float ls = 0.f;
    #pragma unroll 2
    for (int jj = 0; jj < 4; jj++) {
        int j = jbase + jj * 64 + lane;
        const float4* kp = (const float4*)(ko + (size_t)j * 32);
        float s = 0.f;
        #pragma unroll
        for (int qd = 0; qd < 8; qd++) {
            float4 kv = kp[qd];
            s += fmaxf(q[qd * 4 + 0] + kv.x, 0.f) * w2v[qd * 4 + 0];
            s += fmaxf(q[qd * 4 + 1] + kv.y, 0.f) * w2v[qd * 4 + 1];
            s += fmaxf(q[qd * 4 + 2] + kv.z, 0.f) * w2v[qd * 4 + 2];
            s += fmaxf(q[qd * 4 + 3] + kv.w, 0.f) * w2v[qd * 4 + 3];
        }
        s = fmaxf(s + b2, 0.f);
        float av;
        if (a.transposed[z]) av = tile[jj * 64 + lane][wv];
        else av = f32a ? ((const float*)adj)[(size_t)row * 2048 + j]
                       : bf2f(((const u16*)adj)[(size_t)row * 2048 + j]);
        float e = __expf(s * av);
        outw[(size_t)row * 2048 + j] = f2bf(e);
        ls += e;
    }
    #pragma unroll
    for (int o = 32; o > 0; o >>= 1) ls += __shfl_down(ls, o, 64);
    if (lane == 0) a.sums[z][(size_t)blockIdx.y * 2048 + row] = ls;
}

// ---------------- MFMA GEMM, 4-deep pipeline, 4-desc batched ---------------
// rsmode: 0 none, 1 *rs[row], 2 *1/sum_{p<8} rs[row+p*2048]
struct GD4 {
    const void* A[4]; const u16* BT[4]; u16* C[4];
    const u16* bias[4]; const float* rs[4];
    int lda[4], ldb[4], ldc[4], coff[4], ksteps[4], act[4], araw[4], rsmode[4];
};

__global__ __launch_bounds__(256) void gemm16c(GD4 g, const u32* __restrict__ flag) {
    int z = blockIdx.y;
    bool af32 = g.araw[z] && (flag[0] != 0);
    const u16*   A16 = (const u16*)g.A[z];
    const float* A32 = (const float*)g.A[z];
    int lda = g.lda[z], ldb = g.ldb[z];
    int tid = threadIdx.x;
    int lane = tid & 63, wv = tid >> 6;
    int mrow = lane & 15, quad = lane >> 4;
    int m0 = blockIdx.x * 16;
    int c0 = wv * 32;
    size_t aoff = (size_t)(m0 + mrow) * lda + quad * 8;
    const u16* b0p = g.BT[z] + (size_t)(c0 + mrow) * ldb + quad * 8;
    const u16* b1p = g.BT[z] + (size_t)(c0 + 16 + mrow) * ldb + quad * 8;
    f32x4 acc0 = {0.f, 0.f, 0.f, 0.f}, acc1 = {0.f, 0.f, 0.f, 0.f};
    int ks = g.ksteps[z];   // multiple of 4 (64, 8, 4)

    auto aload = [&](int k) -> short8 {
        if (af32) {
            const float4* p = (const float4*)(A32 + aoff + (size_t)k * 32);
            return packbf8(p[0], p[1]);
        }
        return *(const short8*)(A16 + aoff + (size_t)k * 32);
    };
    short8 ab[4], b0b[4], b1b[4];
    #pragma unroll
    for (int i = 0; i < 4; i++) {
        if (i < ks) {
            ab[i]  = aload(i);
            b0b[i] = *(const short8*)(b0p + (size_t)i * 32);
            b1b[i] = *(const short8*)(b1p + (size_t)i * 32);
        }
    }
    for (int k = 0; k < ks; k += 4) {
        #pragma unroll
        for (int u = 0; u < 4; u++) {
            int kc = k + u;
            acc0 = __builtin_amdgcn_mfma_f32_16x16x32_bf16(ab[u], b0b[u], acc0, 0, 0, 0);
            acc1 = __builtin_amdgcn_mfma_f32_16x16x32_bf16(ab[u], b1b[u], acc1, 0, 0, 0);
            int kn = kc + 4;
            if (kn < ks) {
                ab[u]  = aload(kn);
                b0b[u] = *(const short8*)(b0p + (size_t)kn * 32);
                b1b[u] = *(const short8*)(b1p + (size_t)kn * 32);
            }
        }
    }

    const float* rs = g.rs[z];
    int rsmode = g.rsmode[z];
    const u16* bi = g.bias[z];
    u16* C = g.C[z];
    int ldc = g.ldc[z], coff = g.coff[z], act = g.act[z];
    int n0 = c0 + mrow, n1 = n0 + 16;
    float bv0 = bi ? bf2f(bi[n0]) : 0.f;
    float bv1 = bi ? bf2f(bi[n1]) : 0.f;
    #pragma unroll
    for (int r = 0; r < 4; r++) {
        int row = m0 + quad * 4 + r;
        float v0 = acc0[r], v1 = acc1[r];
        if (rsmode == 1) { float sc = rs[row]; v0 *= sc; v1 *= sc; }
        else if (rsmode == 2) {
            float t = 0.f;
            #pragma unroll
            for (int p = 0; p < 8; p++) t += rs[row + p * 2048];
            float sc = 1.f / t;
            v0 *= sc; v1 *= sc;
        }
        v0 += bv0; v1 += bv1;
        if (act) { v0 = seluf(v0); v1 = seluf(v1); }
        C[(size_t)row * ldc + coff + n0] = f2bf(v0);
        C[(size_t)row * ldc + coff + n1] = f2bf(v1);
    }
}

// ---------------- pair gather ----------
__global__ __launch_bounds__(256) void xbuild(
    const u16* __restrict__ he, const u16* __restrict__ hp,
    const int* __restrict__ di, const int* __restrict__ dr, u16* __restrict__ X) {
    int idx = blockIdx.x * 256 + threadIdx.x;  // < B*64
    int d2 = idx & 63;
    int b = idx >> 6;
    int ia = di[b], ic = dr[b];
    u32 ue = ((const u32*)he)[ia * 64 + d2];
    u32 up = ((const u32*)hp)[ic * 64 + d2];
    float lo = bf2f((u16)(ue & 0xffff)) * bf2f((u16)(up & 0xffff));
    float hi = bf2f((u16)(ue >> 16)) * bf2f((u16)(up >> 16));
    ((u32*)X)[idx] = (u32)f2bf(lo) | ((u32)f2bf(hi) << 16);
}

// ---------------- z, sigmoid, loss (FLOAT32 out: out[0]=loss, out[1+b]=sig) --
__global__ __launch_bounds__(256) void zloss(
    const u16* __restrict__ X2, const u16* __restrict__ wpred,
    const u16* __restrict__ bpred, const int* __restrict__ labels,
    float* __restrict__ out, float* __restrict__ part) {
    __shared__ float wp[128];
    __shared__ float ls[256];
    int tid = threadIdx.x;
    if (tid < 128) wp[tid] = bf2f(wpred[tid]);
    __syncthreads();
    int b = blockIdx.x * 256 + tid;
    const uint4* xp = (const uint4*)(X2 + (size_t)b * 128);
    float z = 0.f;
    #pragma unroll
    for (int i = 0; i < 16; i++) {
        uint4 q = xp[i];
        u32 u[4] = {q.x, q.y, q.z, q.w};
        #pragma unroll
        for (int c = 0; c < 4; c++) {
            z += bf2f((u16)(u[c] & 0xffff)) * wp[i * 8 + c * 2];
            z += bf2f((u16)(u[c] >> 16)) * wp[i * 8 + c * 2 + 1];
        }
    }
    z += bf2f(bpred[0]);
    out[1 + b] = 1.f / (1.f + __expf(-z));
    float y = (float)labels[b];
    ls[tid] = fmaxf(z, 0.f) - z * y + log1pf(__expf(-fabsf(z)));
    __syncthreads();
    for (int o = 128; o > 0; o >>= 1) {
        if (tid < o) ls[tid] += ls[tid + o];
        __syncthreads();
    }
    if (tid == 0) part[blockIdx.x] = ls[0];
}

__global__ void finloss(const float* __restrict__ part, float* __restrict__ out) {
    __shared__ float s[64];
    s[threadIdx.x] = part[threadIdx.x];
    __syncthreads();
    for (int o = 32; o > 0; o >>= 1) {
        if (threadIdx.x < o) s[threadIdx.x] += s[threadIdx.x + o];
        __syncthreads();
    }
    if (threadIdx.x == 0) out[0] = s[0] * (1.f / 16384.f);
}

// ---------------- launch ----------------
extern "C" void kernel_launch(void* const* d_in, const int* in_sizes, int n_in,
                              void* d_out, int out_size, void* d_ws, size_t ws_size,
                              hipStream_t stream) {
    const void* e_p_adj = d_in[0];
    const void* e_e_adj = d_in[1];
    const void* p_p_adj = d_in[2];
    const int* in_dis  = (const int*)d_in[3];
    const int* in_drug = (const int*)d_in[4];
    const int* labels  = (const int*)d_in[5];
    float* out = (float*)d_out;

    bool dual = ws_size >= (size_t)24 * 1024 * 1024;

    // -------- workspace layout (~15 MB, +8 MB if dual) --------
    char* ws = (char*)d_ws;
    size_t off = 0;
    auto take = [&](size_t bytes) { char* p = ws + off; off = (off + bytes + 255) & ~(size_t)255; return p; };
    u16*   Wbuf  = (u16*)take((size_t)2048 * 2048 * 2);   // exp weights; later X+X1
    u16*   drugT = (u16*)take((size_t)128 * 2048 * 2);    // --- X2 overlays drugT..A_p ---
    u16*   disT  = (u16*)take((size_t)128 * 2048 * 2);
    float* ko_d  = (float*)take((size_t)2048 * 32 * 4);
    float* qs_d  = (float*)take((size_t)2048 * 32 * 4);
    float* ko_p  = (float*)take((size_t)2048 * 32 * 4);
    float* qs_p  = (float*)take((size_t)2048 * 32 * 4);
    u16*   A_e   = (u16*)take((size_t)2048 * 256 * 2);
    u16*   A_p   = (u16*)take((size_t)2048 * 256 * 2);
    u16*   WcTe  = (u16*)take((size_t)128 * 256 * 2);
    u16*   WcTp  = (u16*)take((size_t)128 * 256 * 2);
    u16*   W1T   = (u16*)take((size_t)128 * 128 * 2);
    u16*   W2T   = (u16*)take((size_t)128 * 128 * 2);
    u16*   b_e   = (u16*)take(256);
    u16*   b_p   = (u16*)take(256);
    u16*   h_e   = (u16*)take((size_t)2048 * 128 * 2);
    u16*   h_p   = (u16*)take((size_t)2048 * 128 * 2);
    float* dinv_e = (float*)take(2048 * 4);
    float* dinv_p = (float*)take(2048 * 4);
    float* sumsD  = (float*)take(8 * 2048 * 4);
    float* sumsP  = (float*)take(8 * 2048 * 4);
    float* part  = (float*)take(64 * 4);
    u16*   canon = (u16*)take((size_t)700000 * 2);
    u32*   flag  = (u32*)take(256);
    u16*   Wbuf2 = dual ? (u16*)take((size_t)2048 * 2048 * 2) : Wbuf;
    u16* X  = Wbuf;
    u16* X1 = Wbuf + (size_t)BB * 128;
    u16* X2 = drugT;   // 4 MB over drugT..A_p

    // -------- canonical parameter table --------
    const int segidx[NSEG] = {6, 7, 14, 18, 8, 22, 11, 24, 26, 28,
                              15, 16, 17, 19, 20, 21,
                              9, 10, 12, 13, 23, 25, 27, 29, 30, 31};
    const int segn[NSEG]   = {262144, 262144, 8192, 8192, 16384, 16384, 16384, 16384, 16384, 16384,
                              32, 32, 1, 32, 32, 1,
                              128, 128, 128, 128, 128, 128, 128, 128, 128, 1};
    CvtArgs ca;
    u16* cp[NSEG];
    {
        int o = 0;
        for (int i = 0; i < NSEG; i++) {
            ca.src[i] = d_in[segidx[i]];
            ca.off[i] = o;
            ca.n[i] = segn[i];
            cp[i] = canon + o;
            o += (segn[i] + 15) & ~15;
        }
    }
    u16 *cdemb = cp[0], *cpemb = cp[1], *cWa1d = cp[2], *cWa1p = cp[3];
    u16 *cWdg = cp[4], *cWd2 = cp[5], *cWpg = cp[6], *cWp3 = cp[7];
    u16 *cW1 = cp[8], *cW2 = cp[9];
    u16 *cba1d = cp[10], *cWa2d = cp[11], *cba2d = cp[12];
    u16 *cba1p = cp[13], *cWa2p = cp[14], *cba2p = cp[15];
    u16 *cbdg_lin = cp[16], *cbdg = cp[17], *cbpg_lin = cp[18], *cbpg = cp[19];
    u16 *cbd2 = cp[20], *cbp3 = cp[21], *cmb1 = cp[22], *cmb2 = cp[23];
    u16 *cWpred = cp[24], *cbpred = cp[25];

    // -------- 0. dtype detection + canonicalization --------
    detectk<<<1, 256, 0, stream>>>(d_in[6], flag);
    cvtk<<<dim3(64, NSEG), 256, 0, stream>>>(ca, canon, flag);

    // -------- 1. prep --------
    tpose_embs<<<dim3(4, 64, 2), dim3(32, 8), 0, stream>>>(cdemb, cpemb, disT, drugT);
    tpose_smalls<<<dim3(4, 4, 6), dim3(32, 8), 0, stream>>>(
        cW1, cW2, cWdg, cWd2, cWpg, cWp3, W1T, W2T, WcTe, WcTp);
    biasc<<<1, 128, 0, stream>>>(cbdg_lin, cbdg, cbd2, b_e, cbpg_lin, cbpg, cbp3, b_p);
    degk<<<dim3(2048, 2), 256, 0, stream>>>(e_e_adj, dinv_e, p_p_adj, dinv_p, flag);
    koqs<<<dim3(2048, 4), 128, 0, stream>>>(cdemb, cpemb, cWa1d, cba1d, cWa1p, cba1p,
                                            ko_d, qs_d, ko_p, qs_p);

    auto setd = [](GD4& g, int z, const void* A, int lda, const u16* BT, int ldb,
                   u16* C, int ldc, int coff, int ks, const u16* bi,
                   const float* rs, int act, int araw, int rm) {
        g.A[z] = A; g.lda[z] = lda; g.BT[z] = BT; g.ldb[z] = ldb;
        g.C[z] = C; g.ldc[z] = ldc; g.coff[z] = coff; g.ksteps[z] = ks;
        g.bias[z] = bi; g.rs[z] = rs; g.act[z] = act; g.araw[z] = araw; g.rsmode[z] = rm;
    };
    auto mkaw = [](const float* qs0, const float* ko0, const u16* w20, const u16* b20,
                   u16* o0, float* s0, int t0,
                   const float* qs1, const float* ko1, const u16* w21, const u16* b21,
                   u16* o1, float* s1, int t1) {
        AW a;
        a.qs[0] = qs0; a.ko[0] = ko0; a.w2[0] = w20; a.b2[0] = b20;
        a.outw[0] = o0; a.sums[0] = s0; a.transposed[0] = t0;
        a.qs[1] = qs1; a.ko[1] = ko1; a.w2[1] = w21; a.b2[1] = b21;
        a.outw[1] = o1; a.sums[1] = s1; a.transposed[1] = t1;
        return a;
    };

    // -------- 2. attention weights + aggregation GEMMs --------
    if (dual) {
        AW aw = mkaw(qs_d, ko_d, cWa2d, cba2d, Wbuf, sumsD, 0,
                     qs_p, ko_p, cWa2p, cba2p, Wbuf2, sumsP, 1);
        attnw5<<<dim3(128, 8, 2), 1024, 0, stream>>>(aw, e_p_adj, flag);
        GD4 g;
        setd(g, 0, Wbuf, 2048, drugT, 2048, A_e, 256, 0, 64, nullptr, sumsD, 0, 0, 2);
        setd(g, 1, e_e_adj, 2048, disT, 2048, A_e, 256, 128, 64, nullptr, dinv_e, 0, 1, 1);
        setd(g, 2, Wbuf2, 2048, disT, 2048, A_p, 256, 0, 64, nullptr, sumsP, 0, 0, 2);
        setd(g, 3, p_p_adj, 2048, drugT, 2048, A_p, 256, 128, 64, nullptr, dinv_p, 0, 1, 1);
        gemm16c<<<dim3(128, 4), 256, 0, stream>>>(g, flag);
    } else {
        AW aw1 = mkaw(qs_d, ko_d, cWa2d, cba2d, Wbuf, sumsD, 0,
                      qs_d, ko_d, cWa2d, cba2d, Wbuf, sumsD, 0);
        attnw5<<<dim3(128, 8, 1), 1024, 0, stream>>>(aw1, e_p_adj, flag);
        GD4 g1;
        setd(g1, 0, Wbuf, 2048, drugT, 2048, A_e, 256, 0, 64, nullptr, sumsD, 0, 0, 2);
        setd(g1, 1, e_e_adj, 2048, disT, 2048, A_e, 256, 128, 64, nullptr, dinv_e, 0, 1, 1);
        setd(g1, 2, Wbuf, 2048, drugT, 2048, A_e, 256, 0, 64, nullptr, sumsD, 0, 0, 2);
        setd(g1, 3, Wbuf, 2048, drugT, 2048, A_e, 256, 0, 64, nullptr, sumsD, 0, 0, 2);
        gemm16c<<<dim3(128, 2), 256, 0, stream>>>(g1, flag);
        AW aw2 = mkaw(qs_p, ko_p, cWa2p, cba2p, Wbuf, sumsP, 1,
                      qs_p, ko_p, cWa2p, cba2p, Wbuf, sumsP, 1);
        attnw5<<<dim3(128, 8, 1), 1024, 0, stream>>>(aw2, e_p_adj, flag);
        GD4 g2;
        setd(g2, 0, Wbuf, 2048, disT, 2048, A_p, 256, 0, 64, nullptr, sumsP, 0, 0, 2);
        setd(g2, 1, p_p_adj, 2048, drugT, 2048, A_p, 256, 128, 64, nullptr, dinv_p, 0, 1, 1);
        setd(g2, 2, Wbuf, 2048, disT, 2048, A_p, 256, 0, 64, nullptr, sumsP, 0, 0, 2);
        setd(g2, 3, Wbuf, 2048, disT, 2048, A_p, 256, 0, 64, nullptr, sumsP, 0, 0, 2);
        gemm16c<<<dim3(128, 2), 256, 0, stream>>>(g2, flag);
    }

    // -------- 3. combine GEMMs (bias + SELU), batched ----------------------
    {
        GD4 g;
        setd(g, 0, A_e, 256, WcTe, 256, h_e, 128, 0, 8, b_e, nullptr, 1, 0, 0);
        setd(g, 1, A_p, 256, WcTp, 256, h_p, 128, 0, 8, b_p, nullptr, 1, 0, 0);
        setd(g, 2, A_e, 256, WcTe, 256, h_e, 128, 0, 8, b_e, nullptr, 1, 0, 0);
        setd(g, 3, A_e, 256, WcTe, 256, h_e, 128, 0, 8, b_e, nullptr, 1, 0, 0);
        gemm16c<<<dim3(128, 2), 256, 0, stream>>>(g, flag);
    }

    // -------- 4. pair MLP --------
    xbuild<<<4096, 256, 0, stream>>>(h_e, h_p, in_dis, in_drug, X);
    {
        GD4 g;
        setd(g, 0, X, 128, W1T, 128, X1, 128, 0, 4, cmb1, nullptr, 1, 0, 0);
        setd(g, 1, X, 128, W1T, 128, X1, 128, 0, 4, cmb1, nullptr, 1, 0, 0);
        setd(g, 2, X, 128, W1T, 128, X1, 128, 0, 4, cmb1, nullptr, 1, 0, 0);
        setd(g, 3, X, 128, W1T, 128, X1, 128, 0, 4, cmb1, nullptr, 1, 0, 0);
        gemm16c<<<dim3(1024, 1), 256, 0, stream>>>(g, flag);
    }
    {
        GD4 g;
        setd(g, 0, X1, 128, W2T, 128, X2, 128, 0, 4, cmb2, nullptr, 1, 0, 0);
        setd(g, 1, X1, 128, W2T, 128, X2, 128, 0, 4, cmb2, nullptr, 1, 0, 0);
        setd(g, 2, X1, 128, W2T, 128, X2, 128, 0, 4, cmb2, nullptr, 1, 0, 0);
        setd(g, 3, X1, 128, W2T, 128, X2, 128, 0, 4, cmb2, nullptr, 1, 0, 0);
        gemm16c<<<dim3(1024, 1), 256, 0, stream>>>(g, flag);
    }

    // -------- 5. z / sigmoid / loss --------
    zloss<<<64, 256, 0, stream>>>(X2, cWpred, cbpred, labels, out, part);
    finloss<<<1, 64, 0, stream>>>(part, out);
}

// Round 10
// 384.828 us; speedup vs baseline: 1.1628x; 1.0051x over previous
//
#include <hip/hip_runtime.h>

#define ND   2048
#define BB   16384

typedef unsigned short u16;
typedef unsigned int u32;
typedef __attribute__((ext_vector_type(8))) short short8;
typedef __attribute__((ext_vector_type(4))) float f32x4;

__device__ inline float bf2f(u16 u) {
    union { u32 i; float f; } v; v.i = ((u32)u) << 16; return v.f;
}
__device__ inline u16 f2bf(float f) {
    union { float f; u32 i; } v; v.f = f;
    u32 i = v.i + 0x7fffu + ((v.i >> 16) & 1u);
    return (u16)(i >> 16);
}
__device__ inline float seluf(float x) {
    const float sc = 1.0507009873554805f, al = 1.6732632423543772f;
    return x > 0.f ? sc * x : sc * al * expm1f(x);
}
__device__ inline short8 packbf8(float4 f0, float4 f1) {
    short8 a;
    a[0] = (short)f2bf(f0.x); a[1] = (short)f2bf(f0.y);
    a[2] = (short)f2bf(f0.z); a[3] = (short)f2bf(f0.w);
    a[4] = (short)f2bf(f1.x); a[5] = (short)f2bf(f1.y);
    a[6] = (short)f2bf(f1.z); a[7] = (short)f2bf(f1.w);
    return a;
}

// ---------------- dtype sniffer ----------------
__global__ void detectk(const void* __restrict__ demb, u32* __restrict__ flag) {
    const u16* p = (const u16*)demb;
    int tid = threadIdx.x;  // 256
    int sane = 0;
    #pragma unroll
    for (int i = 0; i < 2; i++) {
        u16 u = p[4 * tid + 2 * i];
        int e = (u >> 7) & 0xFF;
        if (u == 0 || (e >= 0x66 && e <= 0x8C)) sane++;
    }
    __shared__ int red[256];
    red[tid] = sane; __syncthreads();
    for (int o = 128; o > 0; o >>= 1) {
        if (tid < o) red[tid] += red[tid + o];
        __syncthreads();
    }
    if (tid == 0) flag[0] = (red[0] < 300) ? 1u : 0u;
}

// ---------------- canonical bf16 conversion (26 segments, one launch) -------
#define NSEG 26
struct CvtArgs { const void* src[NSEG]; int off[NSEG]; int n[NSEG]; };

__global__ __launch_bounds__(256) void cvtk(CvtArgs a, u16* __restrict__ base,
                                            const u32* __restrict__ flag) {
    int seg = blockIdx.y;
    int n = a.n[seg];
    const void* s = a.src[seg];
    u16* d = base + a.off[seg];
    bool f32 = flag[0] != 0;
    int stride = gridDim.x * blockDim.x;
    for (int i = blockIdx.x * blockDim.x + threadIdx.x; i < n; i += stride)
        d[i] = f32 ? f2bf(((const float*)s)[i]) : ((const u16*)s)[i];
}

// ---------------- transpose (bf16, tiled 32x32) ----------------
__device__ inline void tpose_body(const u16* in, int R, int C,
                                  u16* out, int ldo, int ooff,
                                  u16 (*tile)[33]) {
    int c0 = blockIdx.x * 32, r0 = blockIdx.y * 32;
    int x = c0 + threadIdx.x;
    for (int i = threadIdx.y; i < 32; i += 8) {
        int r = r0 + i;
        tile[i][threadIdx.x] = (r < R && x < C) ? in[(size_t)r * C + x] : (u16)0;
    }
    __syncthreads();
    int rr = r0 + threadIdx.x;
    for (int i = threadIdx.y; i < 32; i += 8) {
        int cc = c0 + i;
        if (cc < C && rr < R) out[(size_t)cc * ldo + ooff + rr] = tile[threadIdx.x][i];
    }
}

__global__ void tpose_embs(const u16* __restrict__ demb, const u16* __restrict__ pemb,
                           u16* __restrict__ disT, u16* __restrict__ drugT) {
    __shared__ u16 tile[32][33];
    if (blockIdx.z == 0) tpose_body(demb, ND, 128, disT, ND, 0, tile);
    else                 tpose_body(pemb, ND, 128, drugT, ND, 0, tile);
}

__global__ void tpose_smalls(const u16* s0, const u16* s1, const u16* s2,
                             const u16* s3, const u16* s4, const u16* s5,
                             u16* W1T, u16* W2T, u16* WcTe, u16* WcTp) {
    __shared__ u16 tile[32][33];
    const u16* in; u16* out; int ldo, ooff;
    switch (blockIdx.z) {
        case 0:  in = s0; out = W1T;  ldo = 128; ooff = 0;   break;
        case 1:  in = s1; out = W2T;  ldo = 128; ooff = 0;   break;
        case 2:  in = s2; out = WcTe; ldo = 256; ooff = 0;   break;
        case 3:  in = s3; out = WcTe; ldo = 256; ooff = 128; break;
        case 4:  in = s4; out = WcTp; ldo = 256; ooff = 0;   break;
        default: in = s5; out = WcTp; ldo = 256; ooff = 128; break;
    }
    tpose_body(in, 128, 128, out, ldo, ooff, tile);
}

// ---------------- combined biases ----------------
__global__ void biasc(const u16* a0, const u16* a1, const u16* a2, u16* o0,
                      const u16* b0, const u16* b1, const u16* b2, u16* o1) {
    int t = threadIdx.x;  // 128
    o0[t] = f2bf(bf2f(a0[t]) + bf2f(a1[t]) + bf2f(a2[t]));
    o1[t] = f2bf(bf2f(b0[t]) + bf2f(b1[t]) + bf2f(b2[t]));
}

// ---------------- inverse degree ----------------
__global__ __launch_bounds__(256) void degk(
    const void* __restrict__ e_e, float* __restrict__ dinv_e,
    const void* __restrict__ p_p, float* __restrict__ dinv_p,
    const u32* __restrict__ flag) {
    int row = blockIdx.x, tid = threadIdx.x;
    const void* ab = blockIdx.y ? p_p : e_e;
    float* o = blockIdx.y ? dinv_p : dinv_e;
    bool f32 = flag[0] != 0;
    float s = 0.f;
    if (f32) {
        const float4* a4 = (const float4*)((const float*)ab + (size_t)row * 2048) + tid * 2;
        float4 v0 = a4[0], v1 = a4[1];
        s = v0.x + v0.y + v0.z + v0.w + v1.x + v1.y + v1.z + v1.w;
    } else {
        const uint4* a4 = (const uint4*)((const u16*)ab + (size_t)row * 2048) + tid;
        uint4 v = a4[0];
        u32 u[4] = {v.x, v.y, v.z, v.w};
        #pragma unroll
        for (int c = 0; c < 4; c++)
            s += bf2f((u16)(u[c] & 0xffff)) + bf2f((u16)(u[c] >> 16));
    }
    __shared__ float red[256];
    red[tid] = s; __syncthreads();
    for (int ofs = 128; ofs > 0; ofs >>= 1) {
        if (tid < ofs) red[tid] += red[tid + ofs];
        __syncthreads();
    }
    if (tid == 0) o[row] = 1.f / (red[0] + 1e-8f);
}

// ---------------- ko / qs projections ----------
__global__ __launch_bounds__(128) void koqs(
    const u16* __restrict__ demb, const u16* __restrict__ pemb,
    const u16* __restrict__ Wa1d, const u16* __restrict__ ba1d,
    const u16* __restrict__ Wa1p, const u16* __restrict__ ba1p,
    float* __restrict__ ko_d, float* __restrict__ qs_d,
    float* __restrict__ ko_p, float* __restrict__ qs_p) {
    int row = blockIdx.x, m = blockIdx.y, tid = threadIdx.x;
    const u16* src; const u16* W; const u16* bias; float* out;
    switch (m) {
        case 0:  src = pemb; W = Wa1d;            bias = nullptr; out = ko_d; break;
        case 1:  src = demb; W = Wa1d + 128 * 32; bias = ba1d;    out = qs_d; break;
        case 2:  src = demb; W = Wa1p;            bias = nullptr; out = ko_p; break;
        default: src = pemb; W = Wa1p + 128 * 32; bias = ba1p;    out = qs_p; break;
    }
    __shared__ float x[128];
    __shared__ float red[128];
    x[tid] = bf2f(src[(size_t)row * 128 + tid]);
    __syncthreads();
    int a = tid & 31, part = tid >> 5;
    float s = 0.f;
    #pragma unroll
    for (int k = 0; k < 32; k++) s += x[part * 32 + k] * bf2f(W[(part * 32 + k) * 32 + a]);
    red[tid] = s;
    __syncthreads();
    if (part == 0) {
        float t = red[a] + red[a + 32] + red[a + 64] + red[a + 96];
        if (bias) t += bf2f(bias[a]);
        out[(size_t)row * 32 + a] = t;
    }
}

// ---------------- attention v5: 16 rows/block, wave-per-row, line-complete --
// grid (128, 8, nz). block 1024 (16 waves). Transposed staging reads FULL
// 64B lines. __launch_bounds__(1024, 4): 128 VGPR budget so q[32]+w2v[32]
// stay in registers (44-VGPR spill was the round-9 128us pathology).
struct AW {
    const float* qs[2]; const float* ko[2];
    const u16* w2[2]; const u16* b2[2];
    u16* outw[2]; float* sums[2];
    int transposed[2];
};

__global__ __launch_bounds__(1024, 4) void attnw5(AW a, const void* __restrict__ adj,
                                                  const u32* __restrict__ flag) {
    __shared__ float tile[256][17];
    int z = blockIdx.z;
    int tid = threadIdx.x;
    int lane = tid & 63, wv = tid >> 6;      // wv 0..15 = row within block
    int r0 = blockIdx.x * 16;
    int row = r0 + wv;
    int jbase = blockIdx.y * 256;
    bool f32a = flag[0] != 0;
    if (a.transposed[z]) {
        int j = tid >> 2, part = tid & 3;    // j 0..255, part 0..3 (4 elems each)
        if (f32a) {
            const float4* p = (const float4*)((const float*)adj +
                              (size_t)(jbase + j) * 2048 + r0 + part * 4);
            float4 v = *p;
            tile[j][part * 4 + 0] = v.x; tile[j][part * 4 + 1] = v.y;
            tile[j][part * 4 + 2] = v.z; tile[j][part * 4 + 3] = v.w;
        } else {
            const u32* p = (const u32*)((const u16*)adj +
                           (size_t)(jbase + j) * 2048 + r0 + part * 4);
            u32 a0 = p[0], a1 = p[1];
            tile[j][part * 4 + 0] = bf2f((u16)(a0 & 0xffff));
            tile[j][part * 4 + 1] = bf2f((u16)(a0 >> 16));
            tile[j][part * 4 + 2] = bf2f((u16)(a1 & 0xffff));
            tile[j][part * 4 + 3] = bf2f((u16)(a1 >> 16));
        }
        __syncthreads();
    }
    int urow = __builtin_amdgcn_readfirstlane(row);
    const float* qrow = a.qs[z] + (size_t)urow * 32;
    const float* ko = a.ko[z];
    float q[32], w2v[32];
    #pragma unroll
    for (int i = 0; i < 32; i++) q[i] = qrow[i];
    #pragma unroll
    for (int i = 0; i < 32; i++) w2v[i] = bf2f(a.w2[z][i]);
    float b2 = bf2f(a.b2[z][0]);
    u16* outw = a.outw[z];
    float ls = 0.f;
    #pragma unroll 2
    for (int jj = 0; jj < 4; jj++) {
        int j = jbase + jj * 64 + lane;
        const float4* kp = (const float4*)(ko + (size_t)j * 32);
        float s = 0.f;
        #pragma unroll
        for (int qd = 0; qd < 8; qd++) {
            float4 kv = kp[qd];
            s += fmaxf(q[qd * 4 + 0] + kv.x, 0.f) * w2v[qd * 4 + 0];
            s += fmaxf(q[qd * 4 + 1] + kv.y, 0.f) * w2v[qd * 4 + 1];
            s += fmaxf(q[qd * 4 + 2] + kv.z, 0.f) * w2v[qd * 4 + 2];
            s += fmaxf(q[qd * 4 + 3] + kv.w, 0.f) * w2v[qd * 4 + 3];
        }
        s = fmaxf(s + b2, 0.f);
        float av;
        if (a.transposed[z]) av = tile[jj * 64 + lane][wv];
        else av = f32a ? ((const float*)adj)[(size_t)row * 2048 + j]
                       : bf2f(((const u16*)adj)[(size_t)row * 2048 + j]);
        float e = __expf(s * av);
        outw[(size_t)row * 2048 + j] = f2bf(e);
        ls += e;
    }
    #pragma unroll
    for (int o = 32; o > 0; o >>= 1) ls += __shfl_down(ls, o, 64);
    if (lane == 0) a.sums[z][(size_t)blockIdx.y * 2048 + row] = ls;
}

// ---------------- MFMA GEMM, 4-deep pipeline, 4-desc batched ---------------
// __launch_bounds__(256, 2): 256-VGPR budget so the 48 staged fragment regs
// of the 4-deep pipeline stay in registers.
// rsmode: 0 none, 1 *rs[row], 2 *1/sum_{p<8} rs[row+p*2048]
struct GD4 {
    const void* A[4]; const u16* BT[4]; u16* C[4];
    const u16* bias[4]; const float* rs[4];
    int lda[4], ldb[4], ldc[4], coff[4], ksteps[4], act[4], araw[4], rsmode[4];
};

__global__ __launch_bounds__(256, 2) void gemm16c(GD4 g, const u32* __restrict__ flag) {
    int z = blockIdx.y;
    bool af32 = g.araw[z] && (flag[0] != 0);
    const u16*   A16 = (const u16*)g.A[z];
    const float* A32 = (const float*)g.A[z];
    int lda = g.lda[z], ldb = g.ldb[z];
    int tid = threadIdx.x;
    int lane = tid & 63, wv = tid >> 6;
    int mrow = lane & 15, quad = lane >> 4;
    int m0 = blockIdx.x * 16;
    int c0 = wv * 32;
    size_t aoff = (size_t)(m0 + mrow) * lda + quad * 8;
    const u16* b0p = g.BT[z] + (size_t)(c0 + mrow) * ldb + quad * 8;
    const u16* b1p = g.BT[z] + (size_t)(c0 + 16 + mrow) * ldb + quad * 8;
    f32x4 acc0 = {0.f, 0.f, 0.f, 0.f}, acc1 = {0.f, 0.f, 0.f, 0.f};
    int ks = g.ksteps[z];   // multiple of 4 (64, 8, 4)

    auto aload = [&](int k) -> short8 {
        if (af32) {
            const float4* p = (const float4*)(A32 + aoff + (size_t)k * 32);
            return packbf8(p[0], p[1]);
        }
        return *(const short8*)(A16 + aoff + (size_t)k * 32);
    };
    short8 ab[4], b0b[4], b1b[4];
    #pragma unroll
    for (int i = 0; i < 4; i++) {
        if (i < ks) {
            ab[i]  = aload(i);
            b0b[i] = *(const short8*)(b0p + (size_t)i * 32);
            b1b[i] = *(const short8*)(b1p + (size_t)i * 32);
        }
    }
    for (int k = 0; k < ks; k += 4) {
        #pragma unroll
        for (int u = 0; u < 4; u++) {
            int kc = k + u;
            acc0 = __builtin_amdgcn_mfma_f32_16x16x32_bf16(ab[u], b0b[u], acc0, 0, 0, 0);
            acc1 = __builtin_amdgcn_mfma_f32_16x16x32_bf16(ab[u], b1b[u], acc1, 0, 0, 0);
            int kn = kc + 4;
            if (kn < ks) {
                ab[u]  = aload(kn);
                b0b[u] = *(const short8*)(b0p + (size_t)kn * 32);
                b1b[u] = *(const short8*)(b1p + (size_t)kn * 32);
            }
        }
    }

    const float* rs = g.rs[z];
    int rsmode = g.rsmode[z];
    const u16* bi = g.bias[z];
    u16* C = g.C[z];
    int ldc = g.ldc[z], coff = g.coff[z], act = g.act[z];
    int n0 = c0 + mrow, n1 = n0 + 16;
    float bv0 = bi ? bf2f(bi[n0]) : 0.f;
    float bv1 = bi ? bf2f(bi[n1]) : 0.f;
    #pragma unroll
    for (int r = 0; r < 4; r++) {
        int row = m0 + quad * 4 + r;
        float v0 = acc0[r], v1 = acc1[r];
        if (rsmode == 1) { float sc = rs[row]; v0 *= sc; v1 *= sc; }
        else if (rsmode == 2) {
            float t = 0.f;
            #pragma unroll
            for (int p = 0; p < 8; p++) t += rs[row + p * 2048];
            float sc = 1.f / t;
            v0 *= sc; v1 *= sc;
        }
        v0 += bv0; v1 += bv1;
        if (act) { v0 = seluf(v0); v1 = seluf(v1); }
        C[(size_t)row * ldc + coff + n0] = f2bf(v0);
        C[(size_t)row * ldc + coff + n1] = f2bf(v1);
    }
}

// ---------------- pair gather ----------
__global__ __launch_bounds__(256) void xbuild(
    const u16* __restrict__ he, const u16* __restrict__ hp,
    const int* __restrict__ di, const int* __restrict__ dr, u16* __restrict__ X) {
    int idx = blockIdx.x * 256 + threadIdx.x;  // < B*64
    int d2 = idx & 63;
    int b = idx >> 6;
    int ia = di[b], ic = dr[b];
    u32 ue = ((const u32*)he)[ia * 64 + d2];
    u32 up = ((const u32*)hp)[ic * 64 + d2];
    float lo = bf2f((u16)(ue & 0xffff)) * bf2f((u16)(up & 0xffff));
    float hi = bf2f((u16)(ue >> 16)) * bf2f((u16)(up >> 16));
    ((u32*)X)[idx] = (u32)f2bf(lo) | ((u32)f2bf(hi) << 16);
}

// ---------------- z, sigmoid, loss (FLOAT32 out: out[0]=loss, out[1+b]=sig) --
__global__ __launch_bounds__(256) void zloss(
    const u16* __restrict__ X2, const u16* __restrict__ wpred,
    const u16* __restrict__ bpred, const int* __restrict__ labels,
    float* __restrict__ out, float* __restrict__ part) {
    __shared__ float wp[128];
    __shared__ float ls[256];
    int tid = threadIdx.x;
    if (tid < 128) wp[tid] = bf2f(wpred[tid]);
    __syncthreads();
    int b = blockIdx.x * 256 + tid;
    const uint4* xp = (const uint4*)(X2 + (size_t)b * 128);
    float z = 0.f;
    #pragma unroll
    for (int i = 0; i < 16; i++) {
        uint4 q = xp[i];
        u32 u[4] = {q.x, q.y, q.z, q.w};
        #pragma unroll
        for (int c = 0; c < 4; c++) {
            z += bf2f((u16)(u[c] & 0xffff)) * wp[i * 8 + c * 2];
            z += bf2f((u16)(u[c] >> 16)) * wp[i * 8 + c * 2 + 1];
        }
    }
    z += bf2f(bpred[0]);
    out[1 + b] = 1.f / (1.f + __expf(-z));
    float y = (float)labels[b];
    ls[tid] = fmaxf(z, 0.f) - z * y + log1pf(__expf(-fabsf(z)));
    __syncthreads();
    for (int o = 128; o > 0; o >>= 1) {
        if (tid < o) ls[tid] += ls[tid + o];
        __syncthreads();
    }
    if (tid == 0) part[blockIdx.x] = ls[0];
}

__global__ void finloss(const float* __restrict__ part, float* __restrict__ out) {
    __shared__ float s[64];
    s[threadIdx.x] = part[threadIdx.x];
    __syncthreads();
    for (int o = 32; o > 0; o >>= 1) {
        if (threadIdx.x < o) s[threadIdx.x] += s[threadIdx.x + o];
        __syncthreads();
    }
    if (threadIdx.x == 0) out[0] = s[0] * (1.f / 16384.f);
}

// ---------------- launch ----------------
extern "C" void kernel_launch(void* const* d_in, const int* in_sizes, int n_in,
                              void* d_out, int out_size, void* d_ws, size_t ws_size,
                              hipStream_t stream) {
    const void* e_p_adj = d_in[0];
    const void* e_e_adj = d_in[1];
    const void* p_p_adj = d_in[2];
    const int* in_dis  = (const int*)d_in[3];
    const int* in_drug = (const int*)d_in[4];
    const int* labels  = (const int*)d_in[5];
    float* out = (float*)d_out;

    bool dual = ws_size >= (size_t)24 * 1024 * 1024;

    // -------- workspace layout (~15 MB, +8 MB if dual) --------
    char* ws = (char*)d_ws;
    size_t off = 0;
    auto take = [&](size_t bytes) { char* p = ws + off; off = (off + bytes + 255) & ~(size_t)255; return p; };
    u16*   Wbuf  = (u16*)take((size_t)2048 * 2048 * 2);   // exp weights; later X+X1
    u16*   drugT = (u16*)take((size_t)128 * 2048 * 2);    // --- X2 overlays drugT..A_p ---
    u16*   disT  = (u16*)take((size_t)128 * 2048 * 2);
    float* ko_d  = (float*)take((size_t)2048 * 32 * 4);
    float* qs_d  = (float*)take((size_t)2048 * 32 * 4);
    float* ko_p  = (float*)take((size_t)2048 * 32 * 4);
    float* qs_p  = (float*)take((size_t)2048 * 32 * 4);
    u16*   A_e   = (u16*)take((size_t)2048 * 256 * 2);
    u16*   A_p   = (u16*)take((size_t)2048 * 256 * 2);
    u16*   WcTe  = (u16*)take((size_t)128 * 256 * 2);
    u16*   WcTp  = (u16*)take((size_t)128 * 256 * 2);
    u16*   W1T   = (u16*)take((size_t)128 * 128 * 2);
    u16*   W2T   = (u16*)take((size_t)128 * 128 * 2);
    u16*   b_e   = (u16*)take(256);
    u16*   b_p   = (u16*)take(256);
    u16*   h_e   = (u16*)take((size_t)2048 * 128 * 2);
    u16*   h_p   = (u16*)take((size_t)2048 * 128 * 2);
    float* dinv_e = (float*)take(2048 * 4);
    float* dinv_p = (float*)take(2048 * 4);
    float* sumsD  = (float*)take(8 * 2048 * 4);
    float* sumsP  = (float*)take(8 * 2048 * 4);
    float* part  = (float*)take(64 * 4);
    u16*   canon = (u16*)take((size_t)700000 * 2);
    u32*   flag  = (u32*)take(256);
    u16*   Wbuf2 = dual ? (u16*)take((size_t)2048 * 2048 * 2) : Wbuf;
    u16* X  = Wbuf;
    u16* X1 = Wbuf + (size_t)BB * 128;
    u16* X2 = drugT;   // 4 MB over drugT..A_p

    // -------- canonical parameter table --------
    const int segidx[NSEG] = {6, 7, 14, 18, 8, 22, 11, 24, 26, 28,
                              15, 16, 17, 19, 20, 21,
                              9, 10, 12, 13, 23, 25, 27, 29, 30, 31};
    const int segn[NSEG]   = {262144, 262144, 8192, 8192, 16384, 16384, 16384, 16384, 16384, 16384,
                              32, 32, 1, 32, 32, 1,
                              128, 128, 128, 128, 128, 128, 128, 128, 128, 1};
    CvtArgs ca;
    u16* cp[NSEG];
    {
        int o = 0;
        for (int i = 0; i < NSEG; i++) {
            ca.src[i] = d_in[segidx[i]];
            ca.off[i] = o;
            ca.n[i] = segn[i];
            cp[i] = canon + o;
            o += (segn[i] + 15) & ~15;
        }
    }
    u16 *cdemb = cp[0], *cpemb = cp[1], *cWa1d = cp[2], *cWa1p = cp[3];
    u16 *cWdg = cp[4], *cWd2 = cp[5], *cWpg = cp[6], *cWp3 = cp[7];
    u16 *cW1 = cp[8], *cW2 = cp[9];
    u16 *cba1d = cp[10], *cWa2d = cp[11], *cba2d = cp[12];
    u16 *cba1p = cp[13], *cWa2p = cp[14], *cba2p = cp[15];
    u16 *cbdg_lin = cp[16], *cbdg = cp[17], *cbpg_lin = cp[18], *cbpg = cp[19];
    u16 *cbd2 = cp[20], *cbp3 = cp[21], *cmb1 = cp[22], *cmb2 = cp[23];
    u16 *cWpred = cp[24], *cbpred = cp[25];

    // -------- 0. dtype detection + canonicalization --------
    detectk<<<1, 256, 0, stream>>>(d_in[6], flag);
    cvtk<<<dim3(64, NSEG), 256, 0, stream>>>(ca, canon, flag);

    // -------- 1. prep --------
    tpose_embs<<<dim3(4, 64, 2), dim3(32, 8), 0, stream>>>(cdemb, cpemb, disT, drugT);
    tpose_smalls<<<dim3(4, 4, 6), dim3(32, 8), 0, stream>>>(
        cW1, cW2, cWdg, cWd2, cWpg, cWp3, W1T, W2T, WcTe, WcTp);
    biasc<<<1, 128, 0, stream>>>(cbdg_lin, cbdg, cbd2, b_e, cbpg_lin, cbpg, cbp3, b_p);
    degk<<<dim3(2048, 2), 256, 0, stream>>>(e_e_adj, dinv_e, p_p_adj, dinv_p, flag);
    koqs<<<dim3(2048, 4), 128, 0, stream>>>(cdemb, cpemb, cWa1d, cba1d, cWa1p, cba1p,
                                            ko_d, qs_d, ko_p, qs_p);

    auto setd = [](GD4& g, int z, const void* A, int lda, const u16* BT, int ldb,
                   u16* C, int ldc, int coff, int ks, const u16* bi,
                   const float* rs, int act, int araw, int rm) {
        g.A[z] = A; g.lda[z] = lda; g.BT[z] = BT; g.ldb[z] = ldb;
        g.C[z] = C; g.ldc[z] = ldc; g.coff[z] = coff; g.ksteps[z] = ks;
        g.bias[z] = bi; g.rs[z] = rs; g.act[z] = act; g.araw[z] = araw; g.rsmode[z] = rm;
    };
    auto mkaw = [](const float* qs0, const float* ko0, const u16* w20, const u16* b20,
                   u16* o0, float* s0, int t0,
                   const float* qs1, const float* ko1, const u16* w21, const u16* b21,
                   u16* o1, float* s1, int t1) {
        AW a;
        a.qs[0] = qs0; a.ko[0] = ko0; a.w2[0] = w20; a.b2[0] = b20;
        a.outw[0] = o0; a.sums[0] = s0; a.transposed[0] = t0;
        a.qs[1] = qs1; a.ko[1] = ko1; a.w2[1] = w21; a.b2[1] = b21;
        a.outw[1] = o1; a.sums[1] = s1; a.transposed[1] = t1;
        return a;
    };

    // -------- 2. attention weights + aggregation GEMMs --------
    if (dual) {
        AW aw = mkaw(qs_d, ko_d, cWa2d, cba2d, Wbuf, sumsD, 0,
                     qs_p, ko_p, cWa2p, cba2p, Wbuf2, sumsP, 1);
        attnw5<<<dim3(128, 8, 2), 1024, 0, stream>>>(aw, e_p_adj, flag);
        GD4 g;
        setd(g, 0, Wbuf, 2048, drugT, 2048, A_e, 256, 0, 64, nullptr, sumsD, 0, 0, 2);
        setd(g, 1, e_e_adj, 2048, disT, 2048, A_e, 256, 128, 64, nullptr, dinv_e, 0, 1, 1);
        setd(g, 2, Wbuf2, 2048, disT, 2048, A_p, 256, 0, 64, nullptr, sumsP, 0, 0, 2);
        setd(g, 3, p_p_adj, 2048, drugT, 2048, A_p, 256, 128, 64, nullptr, dinv_p, 0, 1, 1);
        gemm16c<<<dim3(128, 4), 256, 0, stream>>>(g, flag);
    } else {
        AW aw1 = mkaw(qs_d, ko_d, cWa2d, cba2d, Wbuf, sumsD, 0,
                      qs_d, ko_d, cWa2d, cba2d, Wbuf, sumsD, 0);
        attnw5<<<dim3(128, 8, 1), 1024, 0, stream>>>(aw1, e_p_adj, flag);
        GD4 g1;
        setd(g1, 0, Wbuf, 2048, drugT, 2048, A_e, 256, 0, 64, nullptr, sumsD, 0, 0, 2);
        setd(g1, 1, e_e_adj, 2048, disT, 2048, A_e, 256, 128, 64, nullptr, dinv_e, 0, 1, 1);
        setd(g1, 2, Wbuf, 2048, drugT, 2048, A_e, 256, 0, 64, nullptr, sumsD, 0, 0, 2);
        setd(g1, 3, Wbuf, 2048, drugT, 2048, A_e, 256, 0, 64, nullptr, sumsD, 0, 0, 2);
        gemm16c<<<dim3(128, 2), 256, 0, stream>>>(g1, flag);
        AW aw2 = mkaw(qs_p, ko_p, cWa2p, cba2p, Wbuf, sumsP, 1,
                      qs_p, ko_p, cWa2p, cba2p, Wbuf, sumsP, 1);
        attnw5<<<dim3(128, 8, 1), 1024, 0, stream>>>(aw2, e_p_adj, flag);
        GD4 g2;
        setd(g2, 0, Wbuf, 2048, disT, 2048, A_p, 256, 0, 64, nullptr, sumsP, 0, 0, 2);
        setd(g2, 1, p_p_adj, 2048, drugT, 2048, A_p, 256, 128, 64, nullptr, dinv_p, 0, 1, 1);
        setd(g2, 2, Wbuf, 2048, disT, 2048, A_p, 256, 0, 64, nullptr, sumsP, 0, 0, 2);
        setd(g2, 3, Wbuf, 2048, disT, 2048, A_p, 256, 0, 64, nullptr, sumsP, 0, 0, 2);
        gemm16c<<<dim3(128, 2), 256, 0, stream>>>(g2, flag);
    }

    // -------- 3. combine GEMMs (bias + SELU), batched ----------------------
    {
        GD4 g;
        setd(g, 0, A_e, 256, WcTe, 256, h_e, 128, 0, 8, b_e, nullptr, 1, 0, 0);
        setd(g, 1, A_p, 256, WcTp, 256, h_p, 128, 0, 8, b_p, nullptr, 1, 0, 0);
        setd(g, 2, A_e, 256, WcTe, 256, h_e, 128, 0, 8, b_e, nullptr, 1, 0, 0);
        setd(g, 3, A_e, 256, WcTe, 256, h_e, 128, 0, 8, b_e, nullptr, 1, 0, 0);
        gemm16c<<<dim3(128, 2), 256, 0, stream>>>(g, flag);
    }

    // -------- 4. pair MLP --------
    xbuild<<<4096, 256, 0, stream>>>(h_e, h_p, in_dis, in_drug, X);
    {
        GD4 g;
        setd(g, 0, X, 128, W1T, 128, X1, 128, 0, 4, cmb1, nullptr, 1, 0, 0);
        setd(g, 1, X, 128, W1T, 128, X1, 128, 0, 4, cmb1, nullptr, 1, 0, 0);
        setd(g, 2, X, 128, W1T, 128, X1, 128, 0, 4, cmb1, nullptr, 1, 0, 0);
        setd(g, 3, X, 128, W1T, 128, X1, 128, 0, 4, cmb1, nullptr, 1, 0, 0);
        gemm16c<<<dim3(1024, 1), 256, 0, stream>>>(g, flag);
    }
    {
        GD4 g;
        setd(g, 0, X1, 128, W2T, 128, X2, 128, 0, 4, cmb2, nullptr, 1, 0, 0);
        setd(g, 1, X1, 128, W2T, 128, X2, 128, 0, 4, cmb2, nullptr, 1, 0, 0);
        setd(g, 2, X1, 128, W2T, 128, X2, 128, 0, 4, cmb2, nullptr, 1, 0, 0);
        setd(g, 3, X1, 128, W2T, 128, X2, 128, 0, 4, cmb2, nullptr, 1, 0, 0);
        gemm16c<<<dim3(1024, 1), 256, 0, stream>>>(g, flag);
    }

    // -------- 5. z / sigmoid / loss --------
    zloss<<<64, 256, 0, stream>>>(X2, cWpred, cbpred, labels, out, part);
    finloss<<<1, 64, 0, stream>>>(part, out);
}

// Round 11
// 300.322 us; speedup vs baseline: 1.4899x; 1.2814x over previous
//
#include <hip/hip_runtime.h>

#define ND   2048
#define BB   16384

typedef unsigned short u16;
typedef unsigned int u32;
typedef __attribute__((ext_vector_type(8))) short short8;
typedef __attribute__((ext_vector_type(4))) float f32x4;

__device__ inline float bf2f(u16 u) {
    union { u32 i; float f; } v; v.i = ((u32)u) << 16; return v.f;
}
__device__ inline u16 f2bf(float f) {
    union { float f; u32 i; } v; v.f = f;
    u32 i = v.i + 0x7fffu + ((v.i >> 16) & 1u);
    return (u16)(i >> 16);
}
__device__ inline float seluf(float x) {
    const float sc = 1.0507009873554805f, al = 1.6732632423543772f;
    return x > 0.f ? sc * x : sc * al * expm1f(x);
}
__device__ inline short8 packbf8(float4 f0, float4 f1) {
    short8 a;
    a[0] = (short)f2bf(f0.x); a[1] = (short)f2bf(f0.y);
    a[2] = (short)f2bf(f0.z); a[3] = (short)f2bf(f0.w);
    a[4] = (short)f2bf(f1.x); a[5] = (short)f2bf(f1.y);
    a[6] = (short)f2bf(f1.z); a[7] = (short)f2bf(f1.w);
    return a;
}

// ---------------- dtype sniffer ----------------
__global__ void detectk(const void* __restrict__ demb, u32* __restrict__ flag) {
    const u16* p = (const u16*)demb;
    int tid = threadIdx.x;  // 256
    int sane = 0;
    #pragma unroll
    for (int i = 0; i < 2; i++) {
        u16 u = p[4 * tid + 2 * i];
        int e = (u >> 7) & 0xFF;
        if (u == 0 || (e >= 0x66 && e <= 0x8C)) sane++;
    }
    __shared__ int red[256];
    red[tid] = sane; __syncthreads();
    for (int o = 128; o > 0; o >>= 1) {
        if (tid < o) red[tid] += red[tid + o];
        __syncthreads();
    }
    if (tid == 0) flag[0] = (red[0] < 300) ? 1u : 0u;
}

// ---------------- canonical bf16 conversion (26 segments, one launch) -------
#define NSEG 26
struct CvtArgs { const void* src[NSEG]; int off[NSEG]; int n[NSEG]; };

__global__ __launch_bounds__(256) void cvtk(CvtArgs a, u16* __restrict__ base,
                                            const u32* __restrict__ flag) {
    int seg = blockIdx.y;
    int n = a.n[seg];
    const void* s = a.src[seg];
    u16* d = base + a.off[seg];
    bool f32 = flag[0] != 0;
    int stride = gridDim.x * blockDim.x;
    for (int i = blockIdx.x * blockDim.x + threadIdx.x; i < n; i += stride)
        d[i] = f32 ? f2bf(((const float*)s)[i]) : ((const u16*)s)[i];
}

// ---------------- transpose (bf16, tiled 32x32) ----------------
__device__ inline void tpose_body(const u16* in, int R, int C,
                                  u16* out, int ldo, int ooff,
                                  u16 (*tile)[33]) {
    int c0 = blockIdx.x * 32, r0 = blockIdx.y * 32;
    int x = c0 + threadIdx.x;
    for (int i = threadIdx.y; i < 32; i += 8) {
        int r = r0 + i;
        tile[i][threadIdx.x] = (r < R && x < C) ? in[(size_t)r * C + x] : (u16)0;
    }
    __syncthreads();
    int rr = r0 + threadIdx.x;
    for (int i = threadIdx.y; i < 32; i += 8) {
        int cc = c0 + i;
        if (cc < C && rr < R) out[(size_t)cc * ldo + ooff + rr] = tile[threadIdx.x][i];
    }
}

__global__ void tpose_embs(const u16* __restrict__ demb, const u16* __restrict__ pemb,
                           u16* __restrict__ disT, u16* __restrict__ drugT) {
    __shared__ u16 tile[32][33];
    if (blockIdx.z == 0) tpose_body(demb, ND, 128, disT, ND, 0, tile);
    else                 tpose_body(pemb, ND, 128, drugT, ND, 0, tile);
}

__global__ void tpose_smalls(const u16* s0, const u16* s1, const u16* s2,
                             const u16* s3, const u16* s4, const u16* s5,
                             u16* W1T, u16* W2T, u16* WcTe, u16* WcTp) {
    __shared__ u16 tile[32][33];
    const u16* in; u16* out; int ldo, ooff;
    switch (blockIdx.z) {
        case 0:  in = s0; out = W1T;  ldo = 128; ooff = 0;   break;
        case 1:  in = s1; out = W2T;  ldo = 128; ooff = 0;   break;
        case 2:  in = s2; out = WcTe; ldo = 256; ooff = 0;   break;
        case 3:  in = s3; out = WcTe; ldo = 256; ooff = 128; break;
        case 4:  in = s4; out = WcTp; ldo = 256; ooff = 0;   break;
        default: in = s5; out = WcTp; ldo = 256; ooff = 128; break;
    }
    tpose_body(in, 128, 128, out, ldo, ooff, tile);
}

// ---------------- combined biases ----------------
__global__ void biasc(const u16* a0, const u16* a1, const u16* a2, u16* o0,
                      const u16* b0, const u16* b1, const u16* b2, u16* o1) {
    int t = threadIdx.x;  // 128
    o0[t] = f2bf(bf2f(a0[t]) + bf2f(a1[t]) + bf2f(a2[t]));
    o1[t] = f2bf(bf2f(b0[t]) + bf2f(b1[t]) + bf2f(b2[t]));
}

// ---------------- inverse degree ----------------
__global__ __launch_bounds__(256) void degk(
    const void* __restrict__ e_e, float* __restrict__ dinv_e,
    const void* __restrict__ p_p, float* __restrict__ dinv_p,
    const u32* __restrict__ flag) {
    int row = blockIdx.x, tid = threadIdx.x;
    const void* ab = blockIdx.y ? p_p : e_e;
    float* o = blockIdx.y ? dinv_p : dinv_e;
    bool f32 = flag[0] != 0;
    float s = 0.f;
    if (f32) {
        const float4* a4 = (const float4*)((const float*)ab + (size_t)row * 2048) + tid * 2;
        float4 v0 = a4[0], v1 = a4[1];
        s = v0.x + v0.y + v0.z + v0.w + v1.x + v1.y + v1.z + v1.w;
    } else {
        const uint4* a4 = (const uint4*)((const u16*)ab + (size_t)row * 2048) + tid;
        uint4 v = a4[0];
        u32 u[4] = {v.x, v.y, v.z, v.w};
        #pragma unroll
        for (int c = 0; c < 4; c++)
            s += bf2f((u16)(u[c] & 0xffff)) + bf2f((u16)(u[c] >> 16));
    }
    __shared__ float red[256];
    red[tid] = s; __syncthreads();
    for (int ofs = 128; ofs > 0; ofs >>= 1) {
        if (tid < ofs) red[tid] += red[tid + ofs];
        __syncthreads();
    }
    if (tid == 0) o[row] = 1.f / (red[0] + 1e-8f);
}

// ---------------- ko / qs projections ----------
__global__ __launch_bounds__(128) void koqs(
    const u16* __restrict__ demb, const u16* __restrict__ pemb,
    const u16* __restrict__ Wa1d, const u16* __restrict__ ba1d,
    const u16* __restrict__ Wa1p, const u16* __restrict__ ba1p,
    float* __restrict__ ko_d, float* __restrict__ qs_d,
    float* __restrict__ ko_p, float* __restrict__ qs_p) {
    int row = blockIdx.x, m = blockIdx.y, tid = threadIdx.x;
    const u16* src; const u16* W; const u16* bias; float* out;
    switch (m) {
        case 0:  src = pemb; W = Wa1d;            bias = nullptr; out = ko_d; break;
        case 1:  src = demb; W = Wa1d + 128 * 32; bias = ba1d;    out = qs_d; break;
        case 2:  src = demb; W = Wa1p;            bias = nullptr; out = ko_p; break;
        default: src = pemb; W = Wa1p + 128 * 32; bias = ba1p;    out = qs_p; break;
    }
    __shared__ float x[128];
    __shared__ float red[128];
    x[tid] = bf2f(src[(size_t)row * 128 + tid]);
    __syncthreads();
    int a = tid & 31, part = tid >> 5;
    float s = 0.f;
    #pragma unroll
    for (int k = 0; k < 32; k++) s += x[part * 32 + k] * bf2f(W[(part * 32 + k) * 32 + a]);
    red[tid] = s;
    __syncthreads();
    if (part == 0) {
        float t = red[a] + red[a + 32] + red[a + 64] + red[a + 96];
        if (bias) t += bf2f(bias[a]);
        out[(size_t)row * 32 + a] = t;
    }
}

// ---------------- attention v6: lane-owns-j, ko in registers ----------------
// grid (8, 64, nz), block 256 (4 waves). Lane owns j (ko[j] loaded ONCE into
// 32 VGPRs). Rows iterate with wave-uniform q (scalar loads). Side 1 stages
// the 256j x 32row adjacency tile in LDS (coalesced-line reads). 8 row-sum
// partials per row -> gemm rsmode=2.
struct AW {
    const float* qs[2]; const float* ko[2];
    const u16* w2[2]; const u16* b2[2];
    u16* outw[2]; float* sums[2];
    int transposed[2];
};

__global__ __launch_bounds__(256, 4) void attnw6(AW a, const void* __restrict__ adj,
                                                 const u32* __restrict__ flag) {
    __shared__ float tile[32][257];
    __shared__ float wpart[4][32];
    int z = blockIdx.z;
    int tid = threadIdx.x;
    int lane = tid & 63, wv = tid >> 6;
    int jl = wv * 64 + lane;                 // j_local 0..255
    int jbase = blockIdx.x * 256;
    int j = jbase + jl;
    int p0 = blockIdx.y * 32;                // 32 rows per block
    bool f32a = flag[0] != 0;
    bool tr = a.transposed[z] != 0;
    const float* adjf = (const float*)adj;
    const u16*   adjh = (const u16*)adj;

    // per-lane ko vector: 32 f32, loaded once
    float kv[32];
    {
        const float4* kp = (const float4*)(a.ko[z] + (size_t)j * 32);
        #pragma unroll
        for (int qd = 0; qd < 8; qd++) {
            float4 v = kp[qd];
            kv[qd * 4 + 0] = v.x; kv[qd * 4 + 1] = v.y;
            kv[qd * 4 + 2] = v.z; kv[qd * 4 + 3] = v.w;
        }
    }
    // wave-uniform constants
    float w2v[32];
    #pragma unroll
    for (int i2 = 0; i2 < 32; i2++) w2v[i2] = bf2f(a.w2[z][i2]);
    float b2 = bf2f(a.b2[z][0]);
    const float* qs = a.qs[z];
    u16* outw = a.outw[z];

    if (tr) {
        // stage A[jbase+tid][p0..p0+32) -> tile[pl][tid]
        if (f32a) {
            const float4* src = (const float4*)(adjf + (size_t)(jbase + tid) * 2048 + p0);
            #pragma unroll
            for (int q8 = 0; q8 < 8; q8++) {
                float4 v = src[q8];
                tile[q8 * 4 + 0][tid] = v.x; tile[q8 * 4 + 1][tid] = v.y;
                tile[q8 * 4 + 2][tid] = v.z; tile[q8 * 4 + 3][tid] = v.w;
            }
        } else {
            const uint4* src = (const uint4*)(adjh + (size_t)(jbase + tid) * 2048 + p0);
            #pragma unroll
            for (int q8 = 0; q8 < 4; q8++) {
                uint4 v = src[q8];
                u32 uu[4] = {v.x, v.y, v.z, v.w};
                #pragma unroll
                for (int c = 0; c < 4; c++) {
                    tile[q8 * 8 + c * 2 + 0][tid] = bf2f((u16)(uu[c] & 0xffff));
                    tile[q8 * 8 + c * 2 + 1][tid] = bf2f((u16)(uu[c] >> 16));
                }
            }
        }
        __syncthreads();
    }

    #pragma unroll 1
    for (int pl = 0; pl < 32; pl++) {
        int row = p0 + pl;
        const float* qrow = qs + (size_t)row * 32;   // wave-uniform -> s_loads
        float s = 0.f;
        #pragma unroll
        for (int aa = 0; aa < 32; aa++)
            s += fmaxf(qrow[aa] + kv[aa], 0.f) * w2v[aa];
        s = fmaxf(s + b2, 0.f);
        float av = tr ? tile[pl][jl]
                      : (f32a ? adjf[(size_t)row * 2048 + j]
                              : bf2f(adjh[(size_t)row * 2048 + j]));
        float e = __expf(s * av);
        outw[(size_t)row * 2048 + j] = f2bf(e);
        float t = e;
        #pragma unroll
        for (int o = 32; o > 0; o >>= 1) t += __shfl_down(t, o, 64);
        if (lane == 0) wpart[wv][pl] = t;
    }
    __syncthreads();
    if (tid < 32)
        a.sums[z][(size_t)blockIdx.x * 2048 + p0 + tid] =
            wpart[0][tid] + wpart[1][tid] + wpart[2][tid] + wpart[3][tid];
}

// ---------------- MFMA GEMM, 4-deep pipeline, 4-desc batched ---------------
// rsmode: 0 none, 1 *rs[row], 2 *1/sum_{p<8} rs[row+p*2048]
struct GD4 {
    const void* A[4]; const u16* BT[4]; u16* C[4];
    const u16* bias[4]; const float* rs[4];
    int lda[4], ldb[4], ldc[4], coff[4], ksteps[4], act[4], araw[4], rsmode[4];
};

__global__ __launch_bounds__(256, 2) void gemm16c(GD4 g, const u32* __restrict__ flag) {
    int z = blockIdx.y;
    bool af32 = g.araw[z] && (flag[0] != 0);
    const u16*   A16 = (const u16*)g.A[z];
    const float* A32 = (const float*)g.A[z];
    int lda = g.lda[z], ldb = g.ldb[z];
    int tid = threadIdx.x;
    int lane = tid & 63, wv = tid >> 6;
    int mrow = lane & 15, quad = lane >> 4;
    int m0 = blockIdx.x * 16;
    int c0 = wv * 32;
    size_t aoff = (size_t)(m0 + mrow) * lda + quad * 8;
    const u16* b0p = g.BT[z] + (size_t)(c0 + mrow) * ldb + quad * 8;
    const u16* b1p = g.BT[z] + (size_t)(c0 + 16 + mrow) * ldb + quad * 8;
    f32x4 acc0 = {0.f, 0.f, 0.f, 0.f}, acc1 = {0.f, 0.f, 0.f, 0.f};
    int ks = g.ksteps[z];   // multiple of 4 (64, 8, 4)

    auto aload = [&](int k) -> short8 {
        if (af32) {
            const float4* p = (const float4*)(A32 + aoff + (size_t)k * 32);
            return packbf8(p[0], p[1]);
        }
        return *(const short8*)(A16 + aoff + (size_t)k * 32);
    };
    short8 ab[4], b0b[4], b1b[4];
    #pragma unroll
    for (int i = 0; i < 4; i++) {
        if (i < ks) {
            ab[i]  = aload(i);
            b0b[i] = *(const short8*)(b0p + (size_t)i * 32);
            b1b[i] = *(const short8*)(b1p + (size_t)i * 32);
        }
    }
    for (int k = 0; k < ks; k += 4) {
        #pragma unroll
        for (int u = 0; u < 4; u++) {
            int kc = k + u;
            acc0 = __builtin_amdgcn_mfma_f32_16x16x32_bf16(ab[u], b0b[u], acc0, 0, 0, 0);
            acc1 = __builtin_amdgcn_mfma_f32_16x16x32_bf16(ab[u], b1b[u], acc1, 0, 0, 0);
            int kn = kc + 4;
            if (kn < ks) {
                ab[u]  = aload(kn);
                b0b[u] = *(const short8*)(b0p + (size_t)kn * 32);
                b1b[u] = *(const short8*)(b1p + (size_t)kn * 32);
            }
        }
    }

    const float* rs = g.rs[z];
    int rsmode = g.rsmode[z];
    const u16* bi = g.bias[z];
    u16* C = g.C[z];
    int ldc = g.ldc[z], coff = g.coff[z], act = g.act[z];
    int n0 = c0 + mrow, n1 = n0 + 16;
    float bv0 = bi ? bf2f(bi[n0]) : 0.f;
    float bv1 = bi ? bf2f(bi[n1]) : 0.f;
    #pragma unroll
    for (int r = 0; r < 4; r++) {
        int row = m0 + quad * 4 + r;
        float v0 = acc0[r], v1 = acc1[r];
        if (rsmode == 1) { float sc = rs[row]; v0 *= sc; v1 *= sc; }
        else if (rsmode == 2) {
            float t = 0.f;
            #pragma unroll
            for (int p = 0; p < 8; p++) t += rs[row + p * 2048];
            float sc = 1.f / t;
            v0 *= sc; v1 *= sc;
        }
        v0 += bv0; v1 += bv1;
        if (act) { v0 = seluf(v0); v1 = seluf(v1); }
        C[(size_t)row * ldc + coff + n0] = f2bf(v0);
        C[(size_t)row * ldc + coff + n1] = f2bf(v1);
    }
}

// ---------------- pair gather ----------
__global__ __launch_bounds__(256) void xbuild(
    const u16* __restrict__ he, const u16* __restrict__ hp,
    const int* __restrict__ di, const int* __restrict__ dr, u16* __restrict__ X) {
    int idx = blockIdx.x * 256 + threadIdx.x;  // < B*64
    int d2 = idx & 63;
    int b = idx >> 6;
    int ia = di[b], ic = dr[b];
    u32 ue = ((const u32*)he)[ia * 64 + d2];
    u32 up = ((const u32*)hp)[ic * 64 + d2];
    float lo = bf2f((u16)(ue & 0xffff)) * bf2f((u16)(up & 0xffff));
    float hi = bf2f((u16)(ue >> 16)) * bf2f((u16)(up >> 16));
    ((u32*)X)[idx] = (u32)f2bf(lo) | ((u32)f2bf(hi) << 16);
}

// ---------------- z, sigmoid, loss (FLOAT32 out: out[0]=loss, out[1+b]=sig) --
__global__ __launch_bounds__(256) void zloss(
    const u16* __restrict__ X2, const u16* __restrict__ wpred,
    const u16* __restrict__ bpred, const int* __restrict__ labels,
    float* __restrict__ out, float* __restrict__ part) {
    __shared__ float wp[128];
    __shared__ float ls[256];
    int tid = threadIdx.x;
    if (tid < 128) wp[tid] = bf2f(wpred[tid]);
    __syncthreads();
    int b = blockIdx.x * 256 + tid;
    const uint4* xp = (const uint4*)(X2 + (size_t)b * 128);
    float z = 0.f;
    #pragma unroll
    for (int i = 0; i < 16; i++) {
        uint4 q = xp[i];
        u32 u[4] = {q.x, q.y, q.z, q.w};
        #pragma unroll
        for (int c = 0; c < 4; c++) {
            z += bf2f((u16)(u[c] & 0xffff)) * wp[i * 8 + c * 2];
            z += bf2f((u16)(u[c] >> 16)) * wp[i * 8 + c * 2 + 1];
        }
    }
    z += bf2f(bpred[0]);
    out[1 + b] = 1.f / (1.f + __expf(-z));
    float y = (float)labels[b];
    ls[tid] = fmaxf(z, 0.f) - z * y + log1pf(__expf(-fabsf(z)));
    __syncthreads();
    for (int o = 128; o > 0; o >>= 1) {
        if (tid < o) ls[tid] += ls[tid + o];
        __syncthreads();
    }
    if (tid == 0) part[blockIdx.x] = ls[0];
}

__global__ void finloss(const float* __restrict__ part, float* __restrict__ out) {
    __shared__ float s[64];
    s[threadIdx.x] = part[threadIdx.x];
    __syncthreads();
    for (int o = 32; o > 0; o >>= 1) {
        if (threadIdx.x < o) s[threadIdx.x] += s[threadIdx.x + o];
        __syncthreads();
    }
    if (threadIdx.x == 0) out[0] = s[0] * (1.f / 16384.f);
}

// ---------------- launch ----------------
extern "C" void kernel_launch(void* const* d_in, const int* in_sizes, int n_in,
                              void* d_out, int out_size, void* d_ws, size_t ws_size,
                              hipStream_t stream) {
    const void* e_p_adj = d_in[0];
    const void* e_e_adj = d_in[1];
    const void* p_p_adj = d_in[2];
    const int* in_dis  = (const int*)d_in[3];
    const int* in_drug = (const int*)d_in[4];
    const int* labels  = (const int*)d_in[5];
    float* out = (float*)d_out;

    // -------- workspace layout --------
    char* ws = (char*)d_ws;
    size_t off = 0;
    auto take = [&](size_t bytes) { char* p = ws + off; off = (off + bytes + 255) & ~(size_t)255; return p; };
    u16*   Wbuf  = (u16*)take((size_t)2048 * 2048 * 2);   // exp weights; later X+X1
    u16*   drugT = (u16*)take((size_t)128 * 2048 * 2);    // --- X2 overlays drugT..A_p ---
    u16*   disT  = (u16*)take((size_t)128 * 2048 * 2);
    float* ko_d  = (float*)take((size_t)2048 * 32 * 4);
    float* qs_d  = (float*)take((size_t)2048 * 32 * 4);
    float* ko_p  = (float*)take((size_t)2048 * 32 * 4);
    float* qs_p  = (float*)take((size_t)2048 * 32 * 4);
    u16*   A_e   = (u16*)take((size_t)2048 * 256 * 2);
    u16*   A_p   = (u16*)take((size_t)2048 * 256 * 2);
    u16*   WcTe  = (u16*)take((size_t)128 * 256 * 2);
    u16*   WcTp  = (u16*)take((size_t)128 * 256 * 2);
    u16*   W1T   = (u16*)take((size_t)128 * 128 * 2);
    u16*   W2T   = (u16*)take((size_t)128 * 128 * 2);
    u16*   b_e   = (u16*)take(256);
    u16*   b_p   = (u16*)take(256);
    u16*   h_e   = (u16*)take((size_t)2048 * 128 * 2);
    u16*   h_p   = (u16*)take((size_t)2048 * 128 * 2);
    float* dinv_e = (float*)take(2048 * 4);
    float* dinv_p = (float*)take(2048 * 4);
    float* sumsD  = (float*)take(8 * 2048 * 4);
    float* sumsP  = (float*)take(8 * 2048 * 4);
    float* part  = (float*)take(64 * 4);
    u16*   canon = (u16*)take((size_t)700000 * 2);
    u32*   flag  = (u32*)take(256);
    bool dual = (ws_size > off) && (ws_size - off) >= ((size_t)2048 * 2048 * 2 + 512);
    u16*   Wbuf2 = dual ? (u16*)take((size_t)2048 * 2048 * 2) : Wbuf;
    u16* X  = Wbuf;
    u16* X1 = Wbuf + (size_t)BB * 128;
    u16* X2 = drugT;   // 4 MB over drugT..A_p

    // -------- canonical parameter table --------
    const int segidx[NSEG] = {6, 7, 14, 18, 8, 22, 11, 24, 26, 28,
                              15, 16, 17, 19, 20, 21,
                              9, 10, 12, 13, 23, 25, 27, 29, 30, 31};
    const int segn[NSEG]   = {262144, 262144, 8192, 8192, 16384, 16384, 16384, 16384, 16384, 16384,
                              32, 32, 1, 32, 32, 1,
                              128, 128, 128, 128, 128, 128, 128, 128, 128, 1};
    CvtArgs ca;
    u16* cp[NSEG];
    {
        int o = 0;
        for (int i = 0; i < NSEG; i++) {
            ca.src[i] = d_in[segidx[i]];
            ca.off[i] = o;
            ca.n[i] = segn[i];
            cp[i] = canon + o;
            o += (segn[i] + 15) & ~15;
        }
    }
    u16 *cdemb = cp[0], *cpemb = cp[1], *cWa1d = cp[2], *cWa1p = cp[3];
    u16 *cWdg = cp[4], *cWd2 = cp[5], *cWpg = cp[6], *cWp3 = cp[7];
    u16 *cW1 = cp[8], *cW2 = cp[9];
    u16 *cba1d = cp[10], *cWa2d = cp[11], *cba2d = cp[12];
    u16 *cba1p = cp[13], *cWa2p = cp[14], *cba2p = cp[15];
    u16 *cbdg_lin = cp[16], *cbdg = cp[17], *cbpg_lin = cp[18], *cbpg = cp[19];
    u16 *cbd2 = cp[20], *cbp3 = cp[21], *cmb1 = cp[22], *cmb2 = cp[23];
    u16 *cWpred = cp[24], *cbpred = cp[25];

    // -------- 0. dtype detection + canonicalization --------
    detectk<<<1, 256, 0, stream>>>(d_in[6], flag);
    cvtk<<<dim3(64, NSEG), 256, 0, stream>>>(ca, canon, flag);

    // -------- 1. prep --------
    tpose_embs<<<dim3(4, 64, 2), dim3(32, 8), 0, stream>>>(cdemb, cpemb, disT, drugT);
    tpose_smalls<<<dim3(4, 4, 6), dim3(32, 8), 0, stream>>>(
        cW1, cW2, cWdg, cWd2, cWpg, cWp3, W1T, W2T, WcTe, WcTp);
    biasc<<<1, 128, 0, stream>>>(cbdg_lin, cbdg, cbd2, b_e, cbpg_lin, cbpg, cbp3, b_p);
    degk<<<dim3(2048, 2), 256, 0, stream>>>(e_e_adj, dinv_e, p_p_adj, dinv_p, flag);
    koqs<<<dim3(2048, 4), 128, 0, stream>>>(cdemb, cpemb, cWa1d, cba1d, cWa1p, cba1p,
                                            ko_d, qs_d, ko_p, qs_p);

    auto setd = [](GD4& g, int z, const void* A, int lda, const u16* BT, int ldb,
                   u16* C, int ldc, int coff, int ks, const u16* bi,
                   const float* rs, int act, int araw, int rm) {
        g.A[z] = A; g.lda[z] = lda; g.BT[z] = BT; g.ldb[z] = ldb;
        g.C[z] = C; g.ldc[z] = ldc; g.coff[z] = coff; g.ksteps[z] = ks;
        g.bias[z] = bi; g.rs[z] = rs; g.act[z] = act; g.araw[z] = araw; g.rsmode[z] = rm;
    };
    auto mkaw = [](const float* qs0, const float* ko0, const u16* w20, const u16* b20,
                   u16* o0, float* s0, int t0,
                   const float* qs1, const float* ko1, const u16* w21, const u16* b21,
                   u16* o1, float* s1, int t1) {
        AW a;
        a.qs[0] = qs0; a.ko[0] = ko0; a.w2[0] = w20; a.b2[0] = b20;
        a.outw[0] = o0; a.sums[0] = s0; a.transposed[0] = t0;
        a.qs[1] = qs1; a.ko[1] = ko1; a.w2[1] = w21; a.b2[1] = b21;
        a.outw[1] = o1; a.sums[1] = s1; a.transposed[1] = t1;
        return a;
    };

    // -------- 2. attention weights + aggregation GEMMs --------
    if (dual) {
        AW aw = mkaw(qs_d, ko_d, cWa2d, cba2d, Wbuf, sumsD, 0,
                     qs_p, ko_p, cWa2p, cba2p, Wbuf2, sumsP, 1);
        attnw6<<<dim3(8, 64, 2), 256, 0, stream>>>(aw, e_p_adj, flag);
        GD4 g;
        setd(g, 0, Wbuf, 2048, drugT, 2048, A_e, 256, 0, 64, nullptr, sumsD, 0, 0, 2);
        setd(g, 1, e_e_adj, 2048, disT, 2048, A_e, 256, 128, 64, nullptr, dinv_e, 0, 1, 1);
        setd(g, 2, Wbuf2, 2048, disT, 2048, A_p, 256, 0, 64, nullptr, sumsP, 0, 0, 2);
        setd(g, 3, p_p_adj, 2048, drugT, 2048, A_p, 256, 128, 64, nullptr, dinv_p, 0, 1, 1);
        gemm16c<<<dim3(128, 4), 256, 0, stream>>>(g, flag);
    } else {
        AW aw1 = mkaw(qs_d, ko_d, cWa2d, cba2d, Wbuf, sumsD, 0,
                      qs_d, ko_d, cWa2d, cba2d, Wbuf, sumsD, 0);
        attnw6<<<dim3(8, 64, 1), 256, 0, stream>>>(aw1, e_p_adj, flag);
        GD4 g1;
        setd(g1, 0, Wbuf, 2048, drugT, 2048, A_e, 256, 0, 64, nullptr, sumsD, 0, 0, 2);
        setd(g1, 1, e_e_adj, 2048, disT, 2048, A_e, 256, 128, 64, nullptr, dinv_e, 0, 1, 1);
        setd(g1, 2, Wbuf, 2048, drugT, 2048, A_e, 256, 0, 64, nullptr, sumsD, 0, 0, 2);
        setd(g1, 3, Wbuf, 2048, drugT, 2048, A_e, 256, 0, 64, nullptr, sumsD, 0, 0, 2);
        gemm16c<<<dim3(128, 2), 256, 0, stream>>>(g1, flag);
        AW aw2 = mkaw(qs_p, ko_p, cWa2p, cba2p, Wbuf, sumsP, 1,
                      qs_p, ko_p, cWa2p, cba2p, Wbuf, sumsP, 1);
        attnw6<<<dim3(8, 64, 1), 256, 0, stream>>>(aw2, e_p_adj, flag);
        GD4 g2;
        setd(g2, 0, Wbuf, 2048, disT, 2048, A_p, 256, 0, 64, nullptr, sumsP, 0, 0, 2);
        setd(g2, 1, p_p_adj, 2048, drugT, 2048, A_p, 256, 128, 64, nullptr, dinv_p, 0, 1, 1);
        setd(g2, 2, Wbuf, 2048, disT, 2048, A_p, 256, 0, 64, nullptr, sumsP, 0, 0, 2);
        setd(g2, 3, Wbuf, 2048, disT, 2048, A_p, 256, 0, 64, nullptr, sumsP, 0, 0, 2);
        gemm16c<<<dim3(128, 2), 256, 0, stream>>>(g2, flag);
    }

    // -------- 3. combine GEMMs (bias + SELU), batched ----------------------
    {
        GD4 g;
        setd(g, 0, A_e, 256, WcTe, 256, h_e, 128, 0, 8, b_e, nullptr, 1, 0, 0);
        setd(g, 1, A_p, 256, WcTp, 256, h_p, 128, 0, 8, b_p, nullptr, 1, 0, 0);
        setd(g, 2, A_e, 256, WcTe, 256, h_e, 128, 0, 8, b_e, nullptr, 1, 0, 0);
        setd(g, 3, A_e, 256, WcTe, 256, h_e, 128, 0, 8, b_e, nullptr, 1, 0, 0);
        gemm16c<<<dim3(128, 2), 256, 0, stream>>>(g, flag);
    }

    // -------- 4. pair MLP --------
    xbuild<<<4096, 256, 0, stream>>>(h_e, h_p, in_dis, in_drug, X);
    {
        GD4 g;
        setd(g, 0, X, 128, W1T, 128, X1, 128, 0, 4, cmb1, nullptr, 1, 0, 0);
        setd(g, 1, X, 128, W1T, 128, X1, 128, 0, 4, cmb1, nullptr, 1, 0, 0);
        setd(g, 2, X, 128, W1T, 128, X1, 128, 0, 4, cmb1, nullptr, 1, 0, 0);
        setd(g, 3, X, 128, W1T, 128, X1, 128, 0, 4, cmb1, nullptr, 1, 0, 0);
        gemm16c<<<dim3(1024, 1), 256, 0, stream>>>(g, flag);
    }
    {
        GD4 g;
        setd(g, 0, X1, 128, W2T, 128, X2, 128, 0, 4, cmb2, nullptr, 1, 0, 0);
        setd(g, 1, X1, 128, W2T, 128, X2, 128, 0, 4, cmb2, nullptr, 1, 0, 0);
        setd(g, 2, X1, 128, W2T, 128, X2, 128, 0, 4, cmb2, nullptr, 1, 0, 0);
        setd(g, 3, X1, 128, W2T, 128, X2, 128, 0, 4, cmb2, nullptr, 1, 0, 0);
        gemm16c<<<dim3(1024, 1), 256, 0, stream>>>(g, flag);
    }

    // -------- 5. z / sigmoid / loss --------
    zloss<<<64, 256, 0, stream>>>(X2, cWpred, cbpred, labels, out, part);
    finloss<<<1, 64, 0, stream>>>(part, out);
}